// Round 10
// baseline (182.870 us; speedup 1.0000x reference)
//
#include <hip/hip_runtime.h>
#include <math.h>

#define NFFT 512
#define HOP  128
#define PADW 256
#define TLEN 64000
#define NF   501
#define NFP  504    // padded frame count for yfr rows
#define FP   256
#define CH   8
#define BATCH 8
#define HID  512
#define MROWS (BATCH * NF)   // 4008
#define FPB  8      // frames per block (stft/istft)
#define NGRP 63     // ceil(NF/FPB)
#define CNCK 8      // cov n-chunks
#define CCK  63     // ceil(NF/CNCK)
#define NSTG 4      // cov frames staged per sync round

#define S2C 0.70710678118654752f

// ---------------- complex helpers ----------------
__device__ __forceinline__ float2 cadd(float2 a, float2 b) { return make_float2(a.x + b.x, a.y + b.y); }
__device__ __forceinline__ float2 csub(float2 a, float2 b) { return make_float2(a.x - b.x, a.y - b.y); }
__device__ __forceinline__ float2 cmul(float2 a, float2 b) { return make_float2(a.x * b.x - a.y * b.y, a.x * b.y + a.y * b.x); }
__device__ __forceinline__ float2 mulnegi(float2 a) { return make_float2(a.y, -a.x); }   // a * (-i)

// forward DFT-8: v[k] = sum_a u[a] * W8^{a k}, W8 = e^{-2pi i/8}
__device__ __forceinline__ void dft8(const float2 u[8], float2 v[8]) {
    float2 a0 = cadd(u[0], u[4]), a1 = cadd(u[1], u[5]), a2 = cadd(u[2], u[6]), a3 = cadd(u[3], u[7]);
    float2 b0 = csub(u[0], u[4]), b1 = csub(u[1], u[5]), b2 = csub(u[2], u[6]), b3 = csub(u[3], u[7]);
    float2 c0 = cadd(a0, a2), c1 = csub(a0, a2), c2 = cadd(a1, a3), c3 = csub(a1, a3);
    v[0] = cadd(c0, c2); v[4] = csub(c0, c2);
    float2 nic3 = mulnegi(c3);
    v[2] = cadd(c1, nic3); v[6] = csub(c1, nic3);
    float2 d1 = make_float2(S2C * (b1.x + b1.y), S2C * (b1.y - b1.x));   // W8^1 * b1
    float2 d2 = mulnegi(b2);                                             // W8^2 * b2
    float2 d3 = make_float2(S2C * (b3.y - b3.x), -S2C * (b3.x + b3.y));  // W8^3 * b3
    float2 e0 = cadd(b0, d2), e1 = csub(b0, d2), e2 = cadd(d1, d3), e3 = csub(d1, d3);
    v[1] = cadd(e0, e2); v[5] = csub(e0, e2);
    float2 nie3 = mulnegi(e3);
    v[3] = cadd(e1, nie3); v[7] = csub(e1, nie3);
}

__device__ __forceinline__ int refl(int j) {
    j = (j < 0) ? -j : j;
    j = (j >= TLEN) ? 2 * (TLEN - 1) - j : j;
    return j;
}

// ---------------- tables: hann window ----------------
__global__ void k_tables(float* tw) {
    int j = threadIdx.x + blockIdx.x * blockDim.x;
    if (j < 512) {
        float ang = (float)(2.0 * M_PI * (double)j / 512.0);
        tw[j] = 0.5f - 0.5f * cosf(ang);
    }
}

// ---------------- STFT: radix-8^3 Stockham FFT on frame-pairs (z = fa + i fb) ----------------
#define A_S 580
#define B_S 544
__global__ __launch_bounds__(256, 4) void k_stft(const float* __restrict__ x,
                                                 const float* __restrict__ tw,
                                                 float2* __restrict__ X,
                                                 float* __restrict__ feat) {
    __shared__ float2 Abuf[4 * A_S];
    __shared__ float2 Bbuf[4 * B_S];
    __shared__ float2 Twd[512];
    int blk = blockIdx.x;
    int g = blk % NGRP;
    int bc = blk / NGRP;
    int c = bc % CH, b = bc / CH;
    int m0 = g * FPB;
    int tid = threadIdx.x;
    const float* xp = x + (size_t)(b * CH + c) * TLEN;

    #pragma unroll
    for (int r = 0; r < 2; ++r) {
        int e = tid + 256 * r;
        float se, ce;
        sincosf((float)e * (float)(2.0 * M_PI / 512.0), &se, &ce);
        Twd[e] = make_float2(ce, -se);
    }

    #pragma unroll
    for (int r = 0; r < 8; ++r) {
        int flat = r * 256 + tid;
        int sig = flat >> 9, t = flat & 511;
        int posa = (m0 + 2 * sig) * HOP + t - PADW;
        float xa = xp[refl(posa)];
        float xb = xp[refl(posa + HOP)];
        float w = tw[t];
        Abuf[sig * A_S + t] = make_float2(xa * w, xb * w);
    }
    __syncthreads();

    int sig = tid >> 6, dft = tid & 63;
    float2 u[8], v[8];

    // stage 1
    {
        const float2* Az = &Abuf[sig * A_S];
        float2* Bu = &Bbuf[sig * B_S];
        #pragma unroll
        for (int a = 0; a < 8; ++a) u[a] = Az[64 * a + dft];
        dft8(u, v);
        #pragma unroll
        for (int k0 = 0; k0 < 8; ++k0) Bu[k0 * 68 + dft] = v[k0];
    }
    __syncthreads();

    // stage 2
    {
        int k0 = dft >> 3, cd = dft & 7;
        const float2* Bu = &Bbuf[sig * B_S];
        float2* Au = &Abuf[sig * A_S];
        #pragma unroll
        for (int bb = 0; bb < 8; ++bb) u[bb] = Bu[k0 * 68 + 8 * bb + cd];
        #pragma unroll
        for (int bb = 1; bb < 8; ++bb) u[bb] = cmul(u[bb], Twd[(8 * bb * k0) & 511]);
        dft8(u, v);
        #pragma unroll
        for (int k1 = 0; k1 < 8; ++k1) Au[(8 * k0 + k1) * 9 + cd] = v[k1];
    }
    __syncthreads();

    // stage 3
    {
        int k0 = dft >> 3, k1 = dft & 7;
        int kk = k0 + 8 * k1;
        const float2* Au = &Abuf[sig * A_S];
        float2* Bz = &Bbuf[sig * B_S];
        #pragma unroll
        for (int cd = 0; cd < 8; ++cd) u[cd] = Au[dft * 9 + cd];
        #pragma unroll
        for (int cd = 1; cd < 8; ++cd) u[cd] = cmul(u[cd], Twd[(cd * kk) & 511]);
        dft8(u, v);
        #pragma unroll
        for (int k2 = 0; k2 < 8; ++k2) Bz[kk + 64 * k2] = v[k2];
    }
    __syncthreads();

    // Hermitian unpack
    {
        int kp = tid;
        int k = kp + 1;
        #pragma unroll
        for (int s = 0; s < 4; ++s) {
            float2 z1 = Bbuf[s * B_S + k];
            float2 z2 = Bbuf[s * B_S + (512 - k)];
            float Ar = 0.5f * (z1.x + z2.x);
            float Ai = 0.5f * (z1.y - z2.y);
            float Br = 0.5f * (z1.y + z2.y);
            float Bi = 0.5f * (z2.x - z1.x);
            int ma = m0 + 2 * s, mb_ = ma + 1;
            if (ma < NF) {
                X[((size_t)(b * NF + ma) * CH + c) * FP + kp] = make_float2(Ar, Ai);
                if (c == 0) feat[((size_t)b * NF + ma) * FP + kp] = sqrtf(Ar * Ar + Ai * Ai);
            }
            if (mb_ < NF) {
                X[((size_t)(b * NF + mb_) * CH + c) * FP + kp] = make_float2(Br, Bi);
                if (c == 0) feat[((size_t)b * NF + mb_) * FP + kp] = sqrtf(Br * Br + Bi * Bi);
            }
        }
    }
}

// ---------------- split-K GEMM partial: P[m][n] = sum_{k in [k0,k0+KSUB)} A[m][k] W[k][n] ----------------
// 128x128 tile, 8x8 microtile, BK=32. One launch covers both splits (sp = bid&1).
template<int KTOT, int KSUB>
__global__ __launch_bounds__(256) void k_gemm_part(const float* __restrict__ A,
                                                   const float* __restrict__ W,
                                                   float* __restrict__ P0,
                                                   float* __restrict__ P1,
                                                   int M) {
    __shared__ float As[32][133];   // [k][row], pad 133 -> conflict-spread scalar writes
    __shared__ float Bs[32][132];   // [k][col]
    int bid = blockIdx.x;
    int sp = bid & 1;
    int nt = (bid >> 1) & 3;
    int mt = bid >> 3;
    int m0 = mt << 7, n0 = nt << 7;
    int k0 = sp * KSUB;
    float* __restrict__ P = sp ? P1 : P0;
    int tid = threadIdx.x;
    int lrowA = tid >> 3;           // 0..31 (+32r)
    int lkA = (tid & 7) * 4;        // 0..28
    int lkB = tid >> 5;             // 0..7 (+8e)
    int lnB = (tid & 31) * 4;
    int tm = tid >> 4, tn = tid & 15;

    float4 acc[16];
    #pragma unroll
    for (int i = 0; i < 16; ++i) acc[i] = make_float4(0.f, 0.f, 0.f, 0.f);

    for (int kt = 0; kt < KSUB; kt += 32) {
        float4 a[4], bb[4];
        #pragma unroll
        for (int r = 0; r < 4; ++r) {
            int row = m0 + lrowA + 32 * r; if (row > M - 1) row = M - 1;
            a[r] = *(const float4*)&A[(size_t)row * KTOT + k0 + kt + lkA];
        }
        #pragma unroll
        for (int e = 0; e < 4; ++e)
            bb[e] = *(const float4*)&W[(size_t)(k0 + kt + lkB + 8 * e) * HID + n0 + lnB];
        if (kt > 0) __syncthreads();
        #pragma unroll
        for (int r = 0; r < 4; ++r) {
            #pragma unroll
            for (int e = 0; e < 4; ++e)
                As[lkA + e][lrowA + 32 * r] = ((const float*)&a[r])[e];
        }
        #pragma unroll
        for (int e = 0; e < 4; ++e)
            *(float4*)&Bs[lkB + 8 * e][lnB] = bb[e];
        __syncthreads();
        #pragma unroll
        for (int k = 0; k < 32; ++k) {
            float4 av0 = *(const float4*)&As[k][tm * 8];
            float4 av1 = *(const float4*)&As[k][tm * 8 + 4];
            float4 bq0 = *(const float4*)&Bs[k][tn * 8];
            float4 bq1 = *(const float4*)&Bs[k][tn * 8 + 4];
            float avs[8] = {av0.x, av0.y, av0.z, av0.w, av1.x, av1.y, av1.z, av1.w};
            #pragma unroll
            for (int r = 0; r < 8; ++r) {
                acc[r * 2].x += avs[r] * bq0.x;
                acc[r * 2].y += avs[r] * bq0.y;
                acc[r * 2].z += avs[r] * bq0.z;
                acc[r * 2].w += avs[r] * bq0.w;
                acc[r * 2 + 1].x += avs[r] * bq1.x;
                acc[r * 2 + 1].y += avs[r] * bq1.y;
                acc[r * 2 + 1].z += avs[r] * bq1.z;
                acc[r * 2 + 1].w += avs[r] * bq1.w;
            }
        }
    }
    #pragma unroll
    for (int r = 0; r < 8; ++r) {
        int m = m0 + tm * 8 + r;
        if (m < M) {
            *(float4*)&P[(size_t)m * HID + n0 + tn * 8]     = acc[r * 2];
            *(float4*)&P[(size_t)m * HID + n0 + tn * 8 + 4] = acc[r * 2 + 1];
        }
    }
}

// ---------------- combine partials + bias + activation (ACT 0=relu, 1=sigmoid) ----------------
template<int ACT>
__global__ __launch_bounds__(256) void k_mlp_fin(float* __restrict__ P0,
                                                 const float* __restrict__ P1,
                                                 const float* __restrict__ bias,
                                                 int M) {
    int i = blockIdx.x * 256 + threadIdx.x;   // float4 index
    if (i >= M * 128) return;                 // M*512/4
    int n0 = (i & 127) * 4;
    float4 v0 = *(const float4*)&P0[(size_t)i * 4];
    float4 v1 = *(const float4*)&P1[(size_t)i * 4];
    float4 bj = *(const float4*)&bias[n0];
    float4 v = make_float4(v0.x + v1.x + bj.x, v0.y + v1.y + bj.y,
                           v0.z + v1.z + bj.z, v0.w + v1.w + bj.w);
    if (ACT == 0) {
        v.x = fmaxf(v.x, 0.f); v.y = fmaxf(v.y, 0.f);
        v.z = fmaxf(v.z, 0.f); v.w = fmaxf(v.w, 0.f);
    } else {
        v.x = 1.f / (1.f + expf(-v.x)); v.y = 1.f / (1.f + expf(-v.y));
        v.z = 1.f / (1.f + expf(-v.z)); v.w = 1.f / (1.f + expf(-v.w));
    }
    *(float4*)&P0[(size_t)i * 4] = v;
}

// ---------------- covariance partials: 4 frames staged per sync round ----------------
// part layout: [nc][b][f][72] float2 : slots 0..63 = R[c][d], 64..71 = rhs[c]
__global__ __launch_bounds__(512) void k_cov(const float2* __restrict__ X,
                                             const float* __restrict__ mo,
                                             float2* __restrict__ part) {
    int blk = blockIdx.x;               // ((b*4 + ftile)*8 + nc)
    int nc = blk & 7;
    int ftile = (blk >> 3) & 3;
    int b = blk >> 5;
    int tid = threadIdx.x;
    int c = tid >> 6;
    int ft = tid & 63;
    int f = ftile * 64 + ft;
    int n0 = nc * CCK;
    int n1 = n0 + CCK; if (n1 > NF) n1 = NF;

    __shared__ float2 vbuf[2][NSTG][CH][64];   // 32 KB

    float ar[8], ai[8];
    #pragma unroll
    for (int d = 0; d < 8; ++d) { ar[d] = 0.f; ai[d] = 0.f; }
    float rr = 0.f, ri = 0.f;

    const float2* Xb = X + (size_t)b * NF * CH * FP;
    const float* mb = mo + (size_t)b * NF * HID;

    #pragma unroll
    for (int r = 0; r < NSTG; ++r) {
        int n = n0 + r;
        if (n < n1) vbuf[0][r][c][ft] = Xb[(size_t)(n * CH + c) * FP + f];
    }
    __syncthreads();
    int cur = 0;
    for (int nb = n0; nb < n1; nb += NSTG) {
        int nbn = nb + NSTG;
        float2 nx[NSTG];
        #pragma unroll
        for (int r = 0; r < NSTG; ++r) {
            int n = nbn + r;
            if (n < n1) nx[r] = Xb[(size_t)(n * CH + c) * FP + f];
        }
        float mts[NSTG], mns[NSTG];
        #pragma unroll
        for (int r = 0; r < NSTG; ++r) {
            int n = nb + r;
            if (n < n1) {
                mts[r] = mb[(size_t)n * HID + f];
                mns[r] = mb[(size_t)n * HID + FP + f];
            }
        }
        #pragma unroll
        for (int r = 0; r < NSTG; ++r) {
            int n = nb + r;
            if (n < n1) {
                float mt = mts[r], mn = mns[r];
                float w = mt + mn;
                float2 xc = vbuf[cur][r][c][ft];
                #pragma unroll
                for (int d = 0; d < 8; ++d) {
                    float2 xd = vbuf[cur][r][d][ft];
                    float pr = xc.x * xd.x + xc.y * xd.y;   // xc * conj(xd)
                    float pi = xc.y * xd.x - xc.x * xd.y;
                    ar[d] += w * pr; ai[d] += w * pi;
                    if (d == 0) { rr += mt * pr; ri += mt * pi; }
                }
            }
        }
        if (nbn < n1) {
            #pragma unroll
            for (int r = 0; r < NSTG; ++r) {
                int n = nbn + r;
                if (n < n1) vbuf[cur ^ 1][r][c][ft] = nx[r];
            }
        }
        __syncthreads();
        cur ^= 1;
    }
    float2* pp = part + (((size_t)nc * BATCH + b) * FP + f) * 72;
    #pragma unroll
    for (int d = 0; d < 8; ++d)
        pp[c * 8 + d] = make_float2(ar[d], ai[d]);
    pp[64 + c] = make_float2(rr, ri);
}

// ---------------- reduce partials + 8x8 complex solve: block = (b, fgroup8) ----------------
__global__ __launch_bounds__(512) void k_cov_solve2(const float2* __restrict__ part,
                                                    float2* __restrict__ wc) {
    int blk = blockIdx.x;          // b*32 + fg
    int fg = blk & 31;
    int b = blk >> 5;
    int tid = threadIdx.x;
    int c = tid >> 6, d = (tid >> 3) & 7, fl = tid & 7;
    int f = fg * 8 + fl;
    float ar = 0.f, ai = 0.f, rr = 0.f, ri = 0.f;
    const float2* pb = part + ((size_t)b * FP + f) * 72;
    #pragma unroll
    for (int nc = 0; nc < CNCK; ++nc) {
        const float2* p = pb + (size_t)nc * BATCH * FP * 72;
        float2 v = p[c * 8 + d];
        ar += v.x; ai += v.y;
        if (d == 0) { float2 u = p[64 + c]; rr += u.x; ri += u.y; }
    }
    __shared__ float2 Am[8][73];
    __shared__ float2 rh[8][8];
    __shared__ float2 sl[8][9];
    Am[fl][c * 9 + d] = make_float2(ar, ai);
    if (d == 0) rh[fl][c] = make_float2(rr, ri);
    __syncthreads();
    if (tid < 8) {
        int ln = tid;
        float2* A = Am[ln];
        float2* r = rh[ln];
        float2* sol = sl[ln];
        for (int kk = 0; kk < 8; ++kk) {
            float2 pp = A[kk * 9 + kk];
            float ip = 1.f / (pp.x * pp.x + pp.y * pp.y);
            float invr = pp.x * ip, invi = -pp.y * ip;
            for (int i = kk + 1; i < 8; ++i) {
                float2 aik = A[i * 9 + kk];
                float fr2 = aik.x * invr - aik.y * invi;
                float fi2 = aik.x * invi + aik.y * invr;
                for (int jj = kk; jj < 8; ++jj) {
                    float2 ak = A[kk * 9 + jj];
                    A[i * 9 + jj].x -= fr2 * ak.x - fi2 * ak.y;
                    A[i * 9 + jj].y -= fr2 * ak.y + fi2 * ak.x;
                }
                r[i].x -= fr2 * r[kk].x - fi2 * r[kk].y;
                r[i].y -= fr2 * r[kk].y + fi2 * r[kk].x;
            }
        }
        for (int kk = 7; kk >= 0; --kk) {
            float sr = r[kk].x, si = r[kk].y;
            for (int jj = kk + 1; jj < 8; ++jj) {
                float2 ak = A[kk * 9 + jj];
                float2 xj = sol[jj];
                sr -= ak.x * xj.x - ak.y * xj.y;
                si -= ak.x * xj.y + ak.y * xj.x;
            }
            float2 pp = A[kk * 9 + kk];
            float ip = 1.f / (pp.x * pp.x + pp.y * pp.y);
            sol[kk].x = (sr * pp.x + si * pp.y) * ip;
            sol[kk].y = (si * pp.x - sr * pp.y) * ip;
        }
        for (int cc = 0; cc < 8; ++cc)   // wc layout [b][c][f], store conj
            wc[((size_t)b * CH + cc) * FP + fg * 8 + ln] = make_float2(sol[cc].x, -sol[cc].y);
    }
}

// ---------------- fused beamform + ISTFT: per-frame windowed iDFT rows, no atomics ----------------
__global__ __launch_bounds__(512) void k_istft_bf(const float2* __restrict__ X,
                                                  const float2* __restrict__ wc,
                                                  float* __restrict__ yfr) {
    __shared__ float2 Zp[4 * 512];          // [sig][k] Hermitian-combined spectra
    __shared__ float2 Gl[16 * 32 * 5];      // [k1][tau][sig] pad 5
    int blk = blockIdx.x;
    int g = blk % NGRP, b = blk / NGRP;
    int m0 = g * FPB;
    int tid = threadIdx.x;

    if (tid < 4) Zp[tid * 512] = make_float2(0.f, 0.f);   // k = 0 (DC dropped)
    const float2* Xb0 = X + (size_t)b * NF * CH * FP;
    const float2* wcb = wc + (size_t)b * CH * FP;
    #pragma unroll
    for (int half = 0; half < 2; ++half) {
        int i = half * 512 + tid;
        int sig = i >> 8, kp = i & 255;     // bin kp -> k = kp+1
        int ma = m0 + 2 * sig, mb_ = ma + 1;
        float2 Xa = make_float2(0.f, 0.f), Xb = make_float2(0.f, 0.f);
        if (ma < NF) {
            #pragma unroll
            for (int c = 0; c < 8; ++c) {
                float2 xv = Xb0[(size_t)(ma * CH + c) * FP + kp];
                float2 wv = wcb[c * FP + kp];
                Xa.x += xv.x * wv.x - xv.y * wv.y;
                Xa.y += xv.x * wv.y + xv.y * wv.x;
            }
        }
        if (mb_ < NF) {
            #pragma unroll
            for (int c = 0; c < 8; ++c) {
                float2 xv = Xb0[(size_t)(mb_ * CH + c) * FP + kp];
                float2 wv = wcb[c * FP + kp];
                Xb.x += xv.x * wv.x - xv.y * wv.y;
                Xb.y += xv.x * wv.y + xv.y * wv.x;
            }
        }
        int k = kp + 1;
        if (k == 256) {
            Zp[sig * 512 + 256] = make_float2(Xa.x, Xb.x);   // Nyquist: real parts only
        } else {
            Zp[sig * 512 + k]       = make_float2(Xa.x - Xb.y, Xa.y + Xb.x);
            Zp[sig * 512 + 512 - k] = make_float2(Xa.x + Xb.y, Xb.x - Xa.y);
        }
    }
    __syncthreads();

    // stage 1: G[k1][tau] = sum_{k2} Zp[k1+16*k2] e^{+i 2pi k2 tau/32}
    {
        int k1 = tid >> 5, tau = tid & 31;
        float sa, ca;
        sincosf((float)tau * (float)(2.0 * M_PI / 32.0), &sa, &ca);
        float stepc = ca, steps = sa;
        float gr[4], gi[4];
        #pragma unroll
        for (int s = 0; s < 4; ++s) { gr[s] = 0.f; gi[s] = 0.f; }
        float cr = 1.f, ci = 0.f;
        #pragma unroll 4
        for (int k2 = 0; k2 < 32; ++k2) {
            int k = k1 + 16 * k2;
            #pragma unroll
            for (int s = 0; s < 4; ++s) {
                float2 z = Zp[s * 512 + k];
                gr[s] += z.x * cr - z.y * ci;
                gi[s] += z.x * ci + z.y * cr;
            }
            float ncr = cr * stepc - ci * steps;
            ci = cr * steps + ci * stepc;
            cr = ncr;
        }
        #pragma unroll
        for (int s = 0; s < 4; ++s)
            Gl[(k1 * 32 + tau) * 5 + s] = make_float2(gr[s], gi[s]);
    }
    __syncthreads();

    // stage 2: y_pair[t] = sum_{k1} G[k1][t&31] e^{+i 2pi k1 t/512}; Re->frame a, Im->frame b
    int t = tid;
    int tau = t & 31;
    float sa2, ca2;
    sincosf((float)t * (float)(2.0 * M_PI / 512.0), &sa2, &ca2);
    float stepc = ca2, steps = sa2;
    float accr[4], acci[4];
    #pragma unroll
    for (int s = 0; s < 4; ++s) { accr[s] = 0.f; acci[s] = 0.f; }
    float cr = 1.f, ci = 0.f;
    #pragma unroll 4
    for (int k1 = 0; k1 < 16; ++k1) {
        #pragma unroll
        for (int s = 0; s < 4; ++s) {
            float2 gv = Gl[(k1 * 32 + tau) * 5 + s];
            accr[s] += gv.x * cr - gv.y * ci;
            acci[s] += gv.x * ci + gv.y * cr;
        }
        float ncr = cr * stepc - ci * steps;
        ci = cr * steps + ci * stepc;
        cr = ncr;
    }
    float wv = (0.5f - 0.5f * ca2) * (1.f / 512.f);   // hann(t) / 512
    #pragma unroll
    for (int s = 0; s < 4; ++s) {
        int ma = m0 + 2 * s, mb_ = ma + 1;
        if (ma < NF)  yfr[((size_t)b * NFP + ma) * 512 + t] = accr[s] * wv;
        if (mb_ < NF) yfr[((size_t)b * NFP + mb_) * 512 + t] = acci[s] * wv;
    }
}

// ---------------- gather overlap-add + wsum normalize ----------------
__global__ __launch_bounds__(256) void k_out(const float* __restrict__ yfr,
                                             float* __restrict__ out) {
    int i = blockIdx.x * blockDim.x + threadIdx.x;
    if (i >= BATCH * TLEN) return;
    int b = i / TLEN;
    int t = i - b * TLEN;
    int p = t + PADW;
    int q = p & 127;
    int m0 = p >> 7;
    float sq, cq;
    sincosf((float)q * (float)(2.0 * M_PI / 512.0), &sq, &cq);
    float w4[4] = {0.5f - 0.5f * cq, 0.5f + 0.5f * sq, 0.5f + 0.5f * cq, 0.5f - 0.5f * sq};
    float val = 0.f, wsum = 0.f;
    const float* yb = yfr + (size_t)b * NFP * 512;
    #pragma unroll
    for (int dm = 0; dm < 4; ++dm) {
        int mm = m0 - dm;
        if (mm >= 0 && mm < NF) {
            val += yb[(size_t)mm * 512 + q + 128 * dm];
            wsum += w4[dm] * w4[dm];
        }
    }
    out[i] = val / fmaxf(wsum, 1e-10f);
}

extern "C" void kernel_launch(void* const* d_in, const int* in_sizes, int n_in,
                              void* d_out, int out_size, void* d_ws, size_t ws_size,
                              hipStream_t stream) {
    const float* x  = (const float*)d_in[0];
    const float* w1 = (const float*)d_in[1];
    const float* b1 = (const float*)d_in[2];
    const float* w2 = (const float*)d_in[3];
    const float* b2 = (const float*)d_in[4];

    float* ws = (float*)d_ws;
    size_t off = 0;
    float*  tw   = ws + off; off += 512;
    float2* X    = (float2*)(ws + off); off += (size_t)BATCH * FP * NF * CH * 2;
    float*  feat = ws + off; off += (size_t)BATCH * NF * FP;     // feat+h reused as `part`
    float*  h    = ws + off; off += (size_t)BATCH * NF * HID;
    float*  mo   = ws + off; off += (size_t)BATCH * NF * HID;
    float2* wc   = (float2*)(ws + off); off += (size_t)BATCH * FP * CH * 2;
    float*  yfr  = ws + off; off += (size_t)BATCH * NFP * 512;   // also split-K scratch (dead until istft)

    // part: [8][8][256][72] float2 = 9.44 MB <= feat+h (12.3 MB), both dead after mlp2
    float2* part = (float2*)feat;

    k_tables<<<2, 256, 0, stream>>>(tw);
    k_stft<<<BATCH * CH * NGRP, 256, 0, stream>>>(x, tw, X, feat);
    // mlp1: split-K 2x (KSUB=128): sp0 -> h, sp1 -> yfr; fin: h = relu(h + yfr + b1)
    k_gemm_part<256, 128><<<32 * 4 * 2, 256, 0, stream>>>(feat, w1, h, yfr, MROWS);
    k_mlp_fin<0><<<(MROWS * 128 + 255) / 256, 256, 0, stream>>>(h, yfr, b1, MROWS);
    // mlp2: split-K 2x (KSUB=256): sp0 -> mo, sp1 -> yfr; fin: mo = sigmoid(mo + yfr + b2)
    k_gemm_part<512, 256><<<32 * 4 * 2, 256, 0, stream>>>(h, w2, mo, yfr, MROWS);
    k_mlp_fin<1><<<(MROWS * 128 + 255) / 256, 256, 0, stream>>>(mo, yfr, b2, MROWS);
    k_cov<<<BATCH * 4 * CNCK, 512, 0, stream>>>(X, mo, part);
    k_cov_solve2<<<BATCH * 32, 512, 0, stream>>>(part, wc);
    k_istft_bf<<<BATCH * NGRP, 512, 0, stream>>>(X, wc, yfr);
    k_out<<<(BATCH * TLEN + 255) / 256, 256, 0, stream>>>(yfr, (float*)d_out);
}

// Round 11
// 129.492 us; speedup vs baseline: 1.4122x; 1.4122x over previous
//
#include <hip/hip_runtime.h>
#include <hip/hip_bf16.h>
#include <math.h>

#define NFFT 512
#define HOP  128
#define PADW 256
#define TLEN 64000
#define NF   501
#define NFP  504
#define FP   256
#define CH   8
#define BATCH 8
#define HID  512
#define MROWS (BATCH * NF)   // 4008
#define FPB  8
#define NGRP 63
#define CNCK 8
#define CCK  63
#define NSTG 4

#define S2C 0.70710678118654752f

typedef short bf16x8 __attribute__((ext_vector_type(8)));   // 8 bf16 (4 VGPRs) per guide
typedef float f32x4 __attribute__((ext_vector_type(4)));

__device__ __forceinline__ unsigned short f2bf(float v) {
    __hip_bfloat16 hb = __float2bfloat16(v);
    return *reinterpret_cast<unsigned short*>(&hb);
}

// ---------------- complex helpers ----------------
__device__ __forceinline__ float2 cadd(float2 a, float2 b) { return make_float2(a.x + b.x, a.y + b.y); }
__device__ __forceinline__ float2 csub(float2 a, float2 b) { return make_float2(a.x - b.x, a.y - b.y); }
__device__ __forceinline__ float2 cmul(float2 a, float2 b) { return make_float2(a.x * b.x - a.y * b.y, a.x * b.y + a.y * b.x); }
__device__ __forceinline__ float2 mulnegi(float2 a) { return make_float2(a.y, -a.x); }

__device__ __forceinline__ void dft8(const float2 u[8], float2 v[8]) {
    float2 a0 = cadd(u[0], u[4]), a1 = cadd(u[1], u[5]), a2 = cadd(u[2], u[6]), a3 = cadd(u[3], u[7]);
    float2 b0 = csub(u[0], u[4]), b1 = csub(u[1], u[5]), b2 = csub(u[2], u[6]), b3 = csub(u[3], u[7]);
    float2 c0 = cadd(a0, a2), c1 = csub(a0, a2), c2 = cadd(a1, a3), c3 = csub(a1, a3);
    v[0] = cadd(c0, c2); v[4] = csub(c0, c2);
    float2 nic3 = mulnegi(c3);
    v[2] = cadd(c1, nic3); v[6] = csub(c1, nic3);
    float2 d1 = make_float2(S2C * (b1.x + b1.y), S2C * (b1.y - b1.x));
    float2 d2 = mulnegi(b2);
    float2 d3 = make_float2(S2C * (b3.y - b3.x), -S2C * (b3.x + b3.y));
    float2 e0 = cadd(b0, d2), e1 = csub(b0, d2), e2 = cadd(d1, d3), e3 = csub(d1, d3);
    v[1] = cadd(e0, e2); v[5] = csub(e0, e2);
    float2 nie3 = mulnegi(e3);
    v[3] = cadd(e1, nie3); v[7] = csub(e1, nie3);
}

__device__ __forceinline__ int refl(int j) {
    j = (j < 0) ? -j : j;
    j = (j >= TLEN) ? 2 * (TLEN - 1) - j : j;
    return j;
}

// ---------------- tables ----------------
__global__ void k_tables(float* tw) {
    int j = threadIdx.x + blockIdx.x * blockDim.x;
    if (j < 512) {
        float ang = (float)(2.0 * M_PI * (double)j / 512.0);
        tw[j] = 0.5f - 0.5f * cosf(ang);
    }
}

// ---------------- weight transpose + bf16 convert: wt[n][k] = bf16(w[k][n]) ----------------
__global__ __launch_bounds__(256) void k_wt(const float* __restrict__ w,
                                            unsigned short* __restrict__ wt, int K) {
    __shared__ float tile[32][33];
    int nt = blockIdx.x & 15;       // 512/32
    int kt = blockIdx.x >> 4;       // K/32
    int tx = threadIdx.x & 31, ty = threadIdx.x >> 5;
    #pragma unroll
    for (int r = 0; r < 4; ++r)
        tile[ty + 8 * r][tx] = w[(size_t)(kt * 32 + ty + 8 * r) * HID + nt * 32 + tx];
    __syncthreads();
    #pragma unroll
    for (int r = 0; r < 4; ++r)
        wt[(size_t)(nt * 32 + ty + 8 * r) * K + kt * 32 + tx] = f2bf(tile[tx][ty + 8 * r]);
}

// ---------------- STFT: radix-8^3 Stockham FFT on frame-pairs; writes X + featbf ----------------
#define A_S 580
#define B_S 544
__global__ __launch_bounds__(256, 4) void k_stft(const float* __restrict__ x,
                                                 const float* __restrict__ tw,
                                                 float2* __restrict__ X,
                                                 unsigned short* __restrict__ featbf) {
    __shared__ float2 Abuf[4 * A_S];
    __shared__ float2 Bbuf[4 * B_S];
    __shared__ float2 Twd[512];
    int blk = blockIdx.x;
    int g = blk % NGRP;
    int bc = blk / NGRP;
    int c = bc % CH, b = bc / CH;
    int m0 = g * FPB;
    int tid = threadIdx.x;
    const float* xp = x + (size_t)(b * CH + c) * TLEN;

    #pragma unroll
    for (int r = 0; r < 2; ++r) {
        int e = tid + 256 * r;
        float se, ce;
        sincosf((float)e * (float)(2.0 * M_PI / 512.0), &se, &ce);
        Twd[e] = make_float2(ce, -se);
    }

    #pragma unroll
    for (int r = 0; r < 8; ++r) {
        int flat = r * 256 + tid;
        int sig = flat >> 9, t = flat & 511;
        int posa = (m0 + 2 * sig) * HOP + t - PADW;
        float xa = xp[refl(posa)];
        float xb = xp[refl(posa + HOP)];
        float w = tw[t];
        Abuf[sig * A_S + t] = make_float2(xa * w, xb * w);
    }
    __syncthreads();

    int sig = tid >> 6, dft = tid & 63;
    float2 u[8], v[8];

    // stage 1
    {
        const float2* Az = &Abuf[sig * A_S];
        float2* Bu = &Bbuf[sig * B_S];
        #pragma unroll
        for (int a = 0; a < 8; ++a) u[a] = Az[64 * a + dft];
        dft8(u, v);
        #pragma unroll
        for (int k0 = 0; k0 < 8; ++k0) Bu[k0 * 68 + dft] = v[k0];
    }
    __syncthreads();

    // stage 2
    {
        int k0 = dft >> 3, cd = dft & 7;
        const float2* Bu = &Bbuf[sig * B_S];
        float2* Au = &Abuf[sig * A_S];
        #pragma unroll
        for (int bb = 0; bb < 8; ++bb) u[bb] = Bu[k0 * 68 + 8 * bb + cd];
        #pragma unroll
        for (int bb = 1; bb < 8; ++bb) u[bb] = cmul(u[bb], Twd[(8 * bb * k0) & 511]);
        dft8(u, v);
        #pragma unroll
        for (int k1 = 0; k1 < 8; ++k1) Au[(8 * k0 + k1) * 9 + cd] = v[k1];
    }
    __syncthreads();

    // stage 3
    {
        int k0 = dft >> 3, k1 = dft & 7;
        int kk = k0 + 8 * k1;
        const float2* Au = &Abuf[sig * A_S];
        float2* Bz = &Bbuf[sig * B_S];
        #pragma unroll
        for (int cd = 0; cd < 8; ++cd) u[cd] = Au[dft * 9 + cd];
        #pragma unroll
        for (int cd = 1; cd < 8; ++cd) u[cd] = cmul(u[cd], Twd[(cd * kk) & 511]);
        dft8(u, v);
        #pragma unroll
        for (int k2 = 0; k2 < 8; ++k2) Bz[kk + 64 * k2] = v[k2];
    }
    __syncthreads();

    // Hermitian unpack
    {
        int kp = tid;
        int k = kp + 1;
        #pragma unroll
        for (int s = 0; s < 4; ++s) {
            float2 z1 = Bbuf[s * B_S + k];
            float2 z2 = Bbuf[s * B_S + (512 - k)];
            float Ar = 0.5f * (z1.x + z2.x);
            float Ai = 0.5f * (z1.y - z2.y);
            float Br = 0.5f * (z1.y + z2.y);
            float Bi = 0.5f * (z2.x - z1.x);
            int ma = m0 + 2 * s, mb_ = ma + 1;
            if (ma < NF) {
                X[((size_t)(b * NF + ma) * CH + c) * FP + kp] = make_float2(Ar, Ai);
                if (c == 0) featbf[((size_t)b * NF + ma) * FP + kp] = f2bf(sqrtf(Ar * Ar + Ai * Ai));
            }
            if (mb_ < NF) {
                X[((size_t)(b * NF + mb_) * CH + c) * FP + kp] = make_float2(Br, Bi);
                if (c == 0) featbf[((size_t)b * NF + mb_) * FP + kp] = f2bf(sqrtf(Br * Br + Bi * Bi));
            }
        }
    }
}

// ---------------- MLP layer via bf16 MFMA: out = act(A[M][K] @ W[K][512] + bias) ----------------
// A bf16 [M][K]; Wt bf16 [512][K] (transposed). Block: 64x128 tile, 4 waves (2x2), per wave 2x4 frags.
// ACT 0: relu -> outbf (bf16); ACT 1: sigmoid -> outf (fp32).
template<int K, int ACT>
__global__ __launch_bounds__(256) void k_mfma_mlp(const unsigned short* __restrict__ Abf,
                                                  const unsigned short* __restrict__ Wt,
                                                  const float* __restrict__ bias,
                                                  float* __restrict__ outf,
                                                  unsigned short* __restrict__ outbf,
                                                  int M) {
    __shared__ unsigned short Al[64][40];    // pad 40: row stride 80 B, 16B-aligned, bank-spread
    __shared__ unsigned short Bl[128][40];
    int bid = blockIdx.x;
    int nt = bid & 3, mt = bid >> 2;
    int m0 = mt * 64, n0 = nt * 128;
    int tid = threadIdx.x;
    int wid = tid >> 6, lane = tid & 63;
    int wm = wid >> 1, wn = wid & 1;
    int lr = lane & 15, lk = (lane >> 4) * 8;

    f32x4 acc[2][4] = {};

    int arow = tid >> 2, ak = (tid & 3) * 8;
    for (int k0 = 0; k0 < K; k0 += 32) {
        int garow = m0 + arow; if (garow > M - 1) garow = M - 1;
        float4 av = *(const float4*)&Abf[(size_t)garow * K + k0 + ak];
        int s0 = tid, s1 = tid + 256;
        float4 bv0 = *(const float4*)&Wt[(size_t)(n0 + (s0 >> 2)) * K + k0 + (s0 & 3) * 8];
        float4 bv1 = *(const float4*)&Wt[(size_t)(n0 + (s1 >> 2)) * K + k0 + (s1 & 3) * 8];
        if (k0 > 0) __syncthreads();
        *(float4*)&Al[arow][ak] = av;
        *(float4*)&Bl[s0 >> 2][(s0 & 3) * 8] = bv0;
        *(float4*)&Bl[s1 >> 2][(s1 & 3) * 8] = bv1;
        __syncthreads();
        bf16x8 af[2], bfr[4];
        af[0] = *(const bf16x8*)&Al[wm * 32 + lr][lk];
        af[1] = *(const bf16x8*)&Al[wm * 32 + 16 + lr][lk];
        #pragma unroll
        for (int nf = 0; nf < 4; ++nf)
            bfr[nf] = *(const bf16x8*)&Bl[wn * 64 + nf * 16 + lr][lk];
        #pragma unroll
        for (int mf = 0; mf < 2; ++mf)
            #pragma unroll
            for (int nf = 0; nf < 4; ++nf)
                acc[mf][nf] = __builtin_amdgcn_mfma_f32_16x16x32_bf16(af[mf], bfr[nf], acc[mf][nf], 0, 0, 0);
    }

    int rbase = (lane >> 4) * 4;
    #pragma unroll
    for (int mf = 0; mf < 2; ++mf) {
        #pragma unroll
        for (int nf = 0; nf < 4; ++nf) {
            int n = n0 + wn * 64 + nf * 16 + lr;
            float bj = bias[n];
            #pragma unroll
            for (int r = 0; r < 4; ++r) {
                int m = m0 + wm * 32 + mf * 16 + rbase + r;
                if (m < M) {
                    float vv = acc[mf][nf][r] + bj;
                    if (ACT == 0) {
                        outbf[(size_t)m * HID + n] = f2bf(fmaxf(vv, 0.f));
                    } else {
                        outf[(size_t)m * HID + n] = 1.f / (1.f + expf(-vv));
                    }
                }
            }
        }
    }
}

// ---------------- covariance partials ----------------
__global__ __launch_bounds__(512) void k_cov(const float2* __restrict__ X,
                                             const float* __restrict__ mo,
                                             float2* __restrict__ part) {
    int blk = blockIdx.x;
    int nc = blk & 7;
    int ftile = (blk >> 3) & 3;
    int b = blk >> 5;
    int tid = threadIdx.x;
    int c = tid >> 6;
    int ft = tid & 63;
    int f = ftile * 64 + ft;
    int n0 = nc * CCK;
    int n1 = n0 + CCK; if (n1 > NF) n1 = NF;

    __shared__ float2 vbuf[2][NSTG][CH][64];

    float ar[8], ai[8];
    #pragma unroll
    for (int d = 0; d < 8; ++d) { ar[d] = 0.f; ai[d] = 0.f; }
    float rr = 0.f, ri = 0.f;

    const float2* Xb = X + (size_t)b * NF * CH * FP;
    const float* mb = mo + (size_t)b * NF * HID;

    #pragma unroll
    for (int r = 0; r < NSTG; ++r) {
        int n = n0 + r;
        if (n < n1) vbuf[0][r][c][ft] = Xb[(size_t)(n * CH + c) * FP + f];
    }
    __syncthreads();
    int cur = 0;
    for (int nb = n0; nb < n1; nb += NSTG) {
        int nbn = nb + NSTG;
        float2 nx[NSTG];
        #pragma unroll
        for (int r = 0; r < NSTG; ++r) {
            int n = nbn + r;
            if (n < n1) nx[r] = Xb[(size_t)(n * CH + c) * FP + f];
        }
        float mts[NSTG], mns[NSTG];
        #pragma unroll
        for (int r = 0; r < NSTG; ++r) {
            int n = nb + r;
            if (n < n1) {
                mts[r] = mb[(size_t)n * HID + f];
                mns[r] = mb[(size_t)n * HID + FP + f];
            }
        }
        #pragma unroll
        for (int r = 0; r < NSTG; ++r) {
            int n = nb + r;
            if (n < n1) {
                float mt = mts[r], mn = mns[r];
                float w = mt + mn;
                float2 xc = vbuf[cur][r][c][ft];
                #pragma unroll
                for (int d = 0; d < 8; ++d) {
                    float2 xd = vbuf[cur][r][d][ft];
                    float pr = xc.x * xd.x + xc.y * xd.y;
                    float pi = xc.y * xd.x - xc.x * xd.y;
                    ar[d] += w * pr; ai[d] += w * pi;
                    if (d == 0) { rr += mt * pr; ri += mt * pi; }
                }
            }
        }
        if (nbn < n1) {
            #pragma unroll
            for (int r = 0; r < NSTG; ++r) {
                int n = nbn + r;
                if (n < n1) vbuf[cur ^ 1][r][c][ft] = nx[r];
            }
        }
        __syncthreads();
        cur ^= 1;
    }
    float2* pp = part + (((size_t)nc * BATCH + b) * FP + f) * 72;
    #pragma unroll
    for (int d = 0; d < 8; ++d)
        pp[c * 8 + d] = make_float2(ar[d], ai[d]);
    pp[64 + c] = make_float2(rr, ri);
}

// ---------------- reduce partials + 8x8 complex solve ----------------
__global__ __launch_bounds__(512) void k_cov_solve2(const float2* __restrict__ part,
                                                    float2* __restrict__ wc) {
    int blk = blockIdx.x;
    int fg = blk & 31;
    int b = blk >> 5;
    int tid = threadIdx.x;
    int c = tid >> 6, d = (tid >> 3) & 7, fl = tid & 7;
    int f = fg * 8 + fl;
    float ar = 0.f, ai = 0.f, rr = 0.f, ri = 0.f;
    const float2* pb = part + ((size_t)b * FP + f) * 72;
    #pragma unroll
    for (int nc = 0; nc < CNCK; ++nc) {
        const float2* p = pb + (size_t)nc * BATCH * FP * 72;
        float2 v = p[c * 8 + d];
        ar += v.x; ai += v.y;
        if (d == 0) { float2 u = p[64 + c]; rr += u.x; ri += u.y; }
    }
    __shared__ float2 Am[8][73];
    __shared__ float2 rh[8][8];
    __shared__ float2 sl[8][9];
    Am[fl][c * 9 + d] = make_float2(ar, ai);
    if (d == 0) rh[fl][c] = make_float2(rr, ri);
    __syncthreads();
    if (tid < 8) {
        int ln = tid;
        float2* A = Am[ln];
        float2* r = rh[ln];
        float2* sol = sl[ln];
        for (int kk = 0; kk < 8; ++kk) {
            float2 pp = A[kk * 9 + kk];
            float ip = 1.f / (pp.x * pp.x + pp.y * pp.y);
            float invr = pp.x * ip, invi = -pp.y * ip;
            for (int i = kk + 1; i < 8; ++i) {
                float2 aik = A[i * 9 + kk];
                float fr2 = aik.x * invr - aik.y * invi;
                float fi2 = aik.x * invi + aik.y * invr;
                for (int jj = kk; jj < 8; ++jj) {
                    float2 ak = A[kk * 9 + jj];
                    A[i * 9 + jj].x -= fr2 * ak.x - fi2 * ak.y;
                    A[i * 9 + jj].y -= fr2 * ak.y + fi2 * ak.x;
                }
                r[i].x -= fr2 * r[kk].x - fi2 * r[kk].y;
                r[i].y -= fr2 * r[kk].y + fi2 * r[kk].x;
            }
        }
        for (int kk = 7; kk >= 0; --kk) {
            float sr = r[kk].x, si = r[kk].y;
            for (int jj = kk + 1; jj < 8; ++jj) {
                float2 ak = A[kk * 9 + jj];
                float2 xj = sol[jj];
                sr -= ak.x * xj.x - ak.y * xj.y;
                si -= ak.x * xj.y + ak.y * xj.x;
            }
            float2 pp = A[kk * 9 + kk];
            float ip = 1.f / (pp.x * pp.x + pp.y * pp.y);
            sol[kk].x = (sr * pp.x + si * pp.y) * ip;
            sol[kk].y = (si * pp.x - sr * pp.y) * ip;
        }
        for (int cc = 0; cc < 8; ++cc)
            wc[((size_t)b * CH + cc) * FP + fg * 8 + ln] = make_float2(sol[cc].x, -sol[cc].y);
    }
}

// ---------------- fused beamform + ISTFT ----------------
__global__ __launch_bounds__(512) void k_istft_bf(const float2* __restrict__ X,
                                                  const float2* __restrict__ wc,
                                                  float* __restrict__ yfr) {
    __shared__ float2 Zp[4 * 512];
    __shared__ float2 Gl[16 * 32 * 5];
    int blk = blockIdx.x;
    int g = blk % NGRP, b = blk / NGRP;
    int m0 = g * FPB;
    int tid = threadIdx.x;

    if (tid < 4) Zp[tid * 512] = make_float2(0.f, 0.f);
    const float2* Xb0 = X + (size_t)b * NF * CH * FP;
    const float2* wcb = wc + (size_t)b * CH * FP;
    #pragma unroll
    for (int half = 0; half < 2; ++half) {
        int i = half * 512 + tid;
        int sig = i >> 8, kp = i & 255;
        int ma = m0 + 2 * sig, mb_ = ma + 1;
        float2 Xa = make_float2(0.f, 0.f), Xb = make_float2(0.f, 0.f);
        if (ma < NF) {
            #pragma unroll
            for (int c = 0; c < 8; ++c) {
                float2 xv = Xb0[(size_t)(ma * CH + c) * FP + kp];
                float2 wv = wcb[c * FP + kp];
                Xa.x += xv.x * wv.x - xv.y * wv.y;
                Xa.y += xv.x * wv.y + xv.y * wv.x;
            }
        }
        if (mb_ < NF) {
            #pragma unroll
            for (int c = 0; c < 8; ++c) {
                float2 xv = Xb0[(size_t)(mb_ * CH + c) * FP + kp];
                float2 wv = wcb[c * FP + kp];
                Xb.x += xv.x * wv.x - xv.y * wv.y;
                Xb.y += xv.x * wv.y + xv.y * wv.x;
            }
        }
        int k = kp + 1;
        if (k == 256) {
            Zp[sig * 512 + 256] = make_float2(Xa.x, Xb.x);
        } else {
            Zp[sig * 512 + k]       = make_float2(Xa.x - Xb.y, Xa.y + Xb.x);
            Zp[sig * 512 + 512 - k] = make_float2(Xa.x + Xb.y, Xb.x - Xa.y);
        }
    }
    __syncthreads();

    {
        int k1 = tid >> 5, tau = tid & 31;
        float sa, ca;
        sincosf((float)tau * (float)(2.0 * M_PI / 32.0), &sa, &ca);
        float stepc = ca, steps = sa;
        float gr[4], gi[4];
        #pragma unroll
        for (int s = 0; s < 4; ++s) { gr[s] = 0.f; gi[s] = 0.f; }
        float cr = 1.f, ci = 0.f;
        #pragma unroll 4
        for (int k2 = 0; k2 < 32; ++k2) {
            int k = k1 + 16 * k2;
            #pragma unroll
            for (int s = 0; s < 4; ++s) {
                float2 z = Zp[s * 512 + k];
                gr[s] += z.x * cr - z.y * ci;
                gi[s] += z.x * ci + z.y * cr;
            }
            float ncr = cr * stepc - ci * steps;
            ci = cr * steps + ci * stepc;
            cr = ncr;
        }
        #pragma unroll
        for (int s = 0; s < 4; ++s)
            Gl[(k1 * 32 + tau) * 5 + s] = make_float2(gr[s], gi[s]);
    }
    __syncthreads();

    int t = tid;
    int tau = t & 31;
    float sa2, ca2;
    sincosf((float)t * (float)(2.0 * M_PI / 512.0), &sa2, &ca2);
    float stepc = ca2, steps = sa2;
    float accr[4], acci[4];
    #pragma unroll
    for (int s = 0; s < 4; ++s) { accr[s] = 0.f; acci[s] = 0.f; }
    float cr = 1.f, ci = 0.f;
    #pragma unroll 4
    for (int k1 = 0; k1 < 16; ++k1) {
        #pragma unroll
        for (int s = 0; s < 4; ++s) {
            float2 gv = Gl[(k1 * 32 + tau) * 5 + s];
            accr[s] += gv.x * cr - gv.y * ci;
            acci[s] += gv.x * ci + gv.y * cr;
        }
        float ncr = cr * stepc - ci * steps;
        ci = cr * steps + ci * stepc;
        cr = ncr;
    }
    float wv = (0.5f - 0.5f * ca2) * (1.f / 512.f);
    #pragma unroll
    for (int s = 0; s < 4; ++s) {
        int ma = m0 + 2 * s, mb_ = ma + 1;
        if (ma < NF)  yfr[((size_t)b * NFP + ma) * 512 + t] = accr[s] * wv;
        if (mb_ < NF) yfr[((size_t)b * NFP + mb_) * 512 + t] = acci[s] * wv;
    }
}

// ---------------- gather overlap-add + wsum normalize ----------------
__global__ __launch_bounds__(256) void k_out(const float* __restrict__ yfr,
                                             float* __restrict__ out) {
    int i = blockIdx.x * blockDim.x + threadIdx.x;
    if (i >= BATCH * TLEN) return;
    int b = i / TLEN;
    int t = i - b * TLEN;
    int p = t + PADW;
    int q = p & 127;
    int m0 = p >> 7;
    float sq, cq;
    sincosf((float)q * (float)(2.0 * M_PI / 512.0), &sq, &cq);
    float w4[4] = {0.5f - 0.5f * cq, 0.5f + 0.5f * sq, 0.5f + 0.5f * cq, 0.5f - 0.5f * sq};
    float val = 0.f, wsum = 0.f;
    const float* yb = yfr + (size_t)b * NFP * 512;
    #pragma unroll
    for (int dm = 0; dm < 4; ++dm) {
        int mm = m0 - dm;
        if (mm >= 0 && mm < NF) {
            val += yb[(size_t)mm * 512 + q + 128 * dm];
            wsum += w4[dm] * w4[dm];
        }
    }
    out[i] = val / fmaxf(wsum, 1e-10f);
}

extern "C" void kernel_launch(void* const* d_in, const int* in_sizes, int n_in,
                              void* d_out, int out_size, void* d_ws, size_t ws_size,
                              hipStream_t stream) {
    const float* x  = (const float*)d_in[0];
    const float* w1 = (const float*)d_in[1];
    const float* b1 = (const float*)d_in[2];
    const float* w2 = (const float*)d_in[3];
    const float* b2 = (const float*)d_in[4];

    float* ws = (float*)d_ws;
    size_t off = 0;
    float*  tw    = ws + off; off += 512;
    float2* X     = (float2*)(ws + off); off += (size_t)BATCH * FP * NF * CH * 2;
    float*  mo    = ws + off; off += (size_t)BATCH * NF * HID;
    float2* wc    = (float2*)(ws + off); off += (size_t)BATCH * FP * CH * 2;
    float*  yfr   = ws + off; off += (size_t)BATCH * NFP * 512;
    float2* part  = (float2*)(ws + off); off += (size_t)CNCK * BATCH * FP * 72 * 2;
    unsigned short* featbf = (unsigned short*)(ws + off); off += (size_t)MROWS * FP / 2;
    unsigned short* hbf    = (unsigned short*)(ws + off); off += (size_t)MROWS * HID / 2;
    unsigned short* wt1bf  = (unsigned short*)(ws + off); off += (size_t)HID * FP / 2;
    unsigned short* wt2bf  = (unsigned short*)(ws + off); off += (size_t)HID * HID / 2;

    k_tables<<<2, 256, 0, stream>>>(tw);
    k_wt<<<16 * 8, 256, 0, stream>>>(w1, wt1bf, FP);      // wt1[n][k], K=256
    k_wt<<<16 * 16, 256, 0, stream>>>(w2, wt2bf, HID);    // wt2[n][k], K=512
    k_stft<<<BATCH * CH * NGRP, 256, 0, stream>>>(x, tw, X, featbf);
    k_mfma_mlp<FP, 0><<<63 * 4, 256, 0, stream>>>(featbf, wt1bf, b1, mo, hbf, MROWS);
    k_mfma_mlp<HID, 1><<<63 * 4, 256, 0, stream>>>(hbf, wt2bf, b2, mo, hbf, MROWS);
    k_cov<<<BATCH * 4 * CNCK, 512, 0, stream>>>(X, mo, part);
    k_cov_solve2<<<BATCH * 32, 512, 0, stream>>>(part, wc);
    k_istft_bf<<<BATCH * NGRP, 512, 0, stream>>>(X, wc, yfr);
    k_out<<<(BATCH * TLEN + 255) / 256, 256, 0, stream>>>(yfr, (float*)d_out);
}

// Round 12
// 123.690 us; speedup vs baseline: 1.4784x; 1.0469x over previous
//
#include <hip/hip_runtime.h>
#include <hip/hip_bf16.h>
#include <math.h>

#define NFFT 512
#define HOP  128
#define PADW 256
#define TLEN 64000
#define NF   501
#define NFP  504
#define FP   256
#define CH   8
#define BATCH 8
#define HID  512
#define MROWS (BATCH * NF)   // 4008
#define FPB  8
#define NGRP 63
#define NSTG 4

#define S2C 0.70710678118654752f

typedef short bf16x8 __attribute__((ext_vector_type(8)));
typedef float f32x4 __attribute__((ext_vector_type(4)));

__device__ __forceinline__ unsigned short f2bf(float v) {
    __hip_bfloat16 hb = __float2bfloat16(v);
    return *reinterpret_cast<unsigned short*>(&hb);
}

// ---------------- complex helpers ----------------
__device__ __forceinline__ float2 cadd(float2 a, float2 b) { return make_float2(a.x + b.x, a.y + b.y); }
__device__ __forceinline__ float2 csub(float2 a, float2 b) { return make_float2(a.x - b.x, a.y - b.y); }
__device__ __forceinline__ float2 cmul(float2 a, float2 b) { return make_float2(a.x * b.x - a.y * b.y, a.x * b.y + a.y * b.x); }
__device__ __forceinline__ float2 mulnegi(float2 a) { return make_float2(a.y, -a.x); }

__device__ __forceinline__ void dft8(const float2 u[8], float2 v[8]) {
    float2 a0 = cadd(u[0], u[4]), a1 = cadd(u[1], u[5]), a2 = cadd(u[2], u[6]), a3 = cadd(u[3], u[7]);
    float2 b0 = csub(u[0], u[4]), b1 = csub(u[1], u[5]), b2 = csub(u[2], u[6]), b3 = csub(u[3], u[7]);
    float2 c0 = cadd(a0, a2), c1 = csub(a0, a2), c2 = cadd(a1, a3), c3 = csub(a1, a3);
    v[0] = cadd(c0, c2); v[4] = csub(c0, c2);
    float2 nic3 = mulnegi(c3);
    v[2] = cadd(c1, nic3); v[6] = csub(c1, nic3);
    float2 d1 = make_float2(S2C * (b1.x + b1.y), S2C * (b1.y - b1.x));
    float2 d2 = mulnegi(b2);
    float2 d3 = make_float2(S2C * (b3.y - b3.x), -S2C * (b3.x + b3.y));
    float2 e0 = cadd(b0, d2), e1 = csub(b0, d2), e2 = cadd(d1, d3), e3 = csub(d1, d3);
    v[1] = cadd(e0, e2); v[5] = csub(e0, e2);
    float2 nie3 = mulnegi(e3);
    v[3] = cadd(e1, nie3); v[7] = csub(e1, nie3);
}

__device__ __forceinline__ int refl(int j) {
    j = (j < 0) ? -j : j;
    j = (j >= TLEN) ? 2 * (TLEN - 1) - j : j;
    return j;
}

// ---------------- prep: hann table + both weight transposes (1 launch) ----------------
__global__ __launch_bounds__(256) void k_prep(const float* __restrict__ w1,
                                              const float* __restrict__ w2,
                                              float* __restrict__ tw,
                                              unsigned short* __restrict__ wt1,
                                              unsigned short* __restrict__ wt2) {
    __shared__ float tile[32][33];
    int bid = blockIdx.x;
    if (bid == 384) {
        #pragma unroll
        for (int r = 0; r < 2; ++r) {
            int e = threadIdx.x + 256 * r;
            float ang = (float)(2.0 * M_PI * (double)e / 512.0);
            tw[e] = 0.5f - 0.5f * cosf(ang);
        }
        return;
    }
    const float* w; unsigned short* wt; int K, lb;
    if (bid < 128) { w = w1; wt = wt1; K = 256; lb = bid; }
    else           { w = w2; wt = wt2; K = 512; lb = bid - 128; }
    int nt = lb & 15, kt = lb >> 4;
    int tx = threadIdx.x & 31, ty = threadIdx.x >> 5;
    #pragma unroll
    for (int r = 0; r < 4; ++r)
        tile[ty + 8 * r][tx] = w[(size_t)(kt * 32 + ty + 8 * r) * HID + nt * 32 + tx];
    __syncthreads();
    #pragma unroll
    for (int r = 0; r < 4; ++r)
        wt[(size_t)(nt * 32 + ty + 8 * r) * K + kt * 32 + tx] = f2bf(tile[tx][ty + 8 * r]);
}

// ---------------- STFT: radix-8^3 Stockham FFT on frame-pairs; x staged once in LDS ----------------
#define A_S 580
#define B_S 544
__global__ __launch_bounds__(256, 4) void k_stft(const float* __restrict__ x,
                                                 const float* __restrict__ tw,
                                                 float2* __restrict__ X,
                                                 unsigned short* __restrict__ featbf) {
    __shared__ float2 Abuf[4 * A_S];
    __shared__ float2 Bbuf[4 * B_S];
    __shared__ float2 Twd[512];
    int blk = blockIdx.x;
    int g = blk % NGRP;
    int bc = blk / NGRP;
    int c = bc % CH, b = bc / CH;
    int m0 = g * FPB;
    int tid = threadIdx.x;
    const float* xp = x + (size_t)(b * CH + c) * TLEN;

    #pragma unroll
    for (int r = 0; r < 2; ++r) {
        int e = tid + 256 * r;
        float se, ce;
        sincosf((float)e * (float)(2.0 * M_PI / 512.0), &se, &ce);
        Twd[e] = make_float2(ce, -se);
    }

    // stage the 1536-sample span once (Bbuf as scratch; dead until stage 1)
    float* xs = (float*)Bbuf;
    int base = m0 * HOP - PADW;
    #pragma unroll
    for (int r = 0; r < 6; ++r) {
        int i = r * 256 + tid;
        xs[i] = xp[refl(base + i)];
    }
    __syncthreads();

    // build z[sig][t] = w[t]*(x_a[t] + i x_b[t]) from LDS
    #pragma unroll
    for (int r = 0; r < 8; ++r) {
        int flat = r * 256 + tid;
        int sig = flat >> 9, t = flat & 511;
        float w = tw[t];
        Abuf[sig * A_S + t] = make_float2(xs[2 * sig * 128 + t] * w,
                                          xs[(2 * sig + 1) * 128 + t] * w);
    }
    __syncthreads();

    int sig = tid >> 6, dft = tid & 63;
    float2 u[8], v[8];

    // stage 1
    {
        const float2* Az = &Abuf[sig * A_S];
        float2* Bu = &Bbuf[sig * B_S];
        #pragma unroll
        for (int a = 0; a < 8; ++a) u[a] = Az[64 * a + dft];
        dft8(u, v);
        #pragma unroll
        for (int k0 = 0; k0 < 8; ++k0) Bu[k0 * 68 + dft] = v[k0];
    }
    __syncthreads();

    // stage 2
    {
        int k0 = dft >> 3, cd = dft & 7;
        const float2* Bu = &Bbuf[sig * B_S];
        float2* Au = &Abuf[sig * A_S];
        #pragma unroll
        for (int bb = 0; bb < 8; ++bb) u[bb] = Bu[k0 * 68 + 8 * bb + cd];
        #pragma unroll
        for (int bb = 1; bb < 8; ++bb) u[bb] = cmul(u[bb], Twd[(8 * bb * k0) & 511]);
        dft8(u, v);
        #pragma unroll
        for (int k1 = 0; k1 < 8; ++k1) Au[(8 * k0 + k1) * 9 + cd] = v[k1];
    }
    __syncthreads();

    // stage 3
    {
        int k0 = dft >> 3, k1 = dft & 7;
        int kk = k0 + 8 * k1;
        const float2* Au = &Abuf[sig * A_S];
        float2* Bz = &Bbuf[sig * B_S];
        #pragma unroll
        for (int cd = 0; cd < 8; ++cd) u[cd] = Au[dft * 9 + cd];
        #pragma unroll
        for (int cd = 1; cd < 8; ++cd) u[cd] = cmul(u[cd], Twd[(cd * kk) & 511]);
        dft8(u, v);
        #pragma unroll
        for (int k2 = 0; k2 < 8; ++k2) Bz[kk + 64 * k2] = v[k2];
    }
    __syncthreads();

    // Hermitian unpack
    {
        int kp = tid;
        int k = kp + 1;
        #pragma unroll
        for (int s = 0; s < 4; ++s) {
            float2 z1 = Bbuf[s * B_S + k];
            float2 z2 = Bbuf[s * B_S + (512 - k)];
            float Ar = 0.5f * (z1.x + z2.x);
            float Ai = 0.5f * (z1.y - z2.y);
            float Br = 0.5f * (z1.y + z2.y);
            float Bi = 0.5f * (z2.x - z1.x);
            int ma = m0 + 2 * s, mb_ = ma + 1;
            if (ma < NF) {
                X[((size_t)(b * NF + ma) * CH + c) * FP + kp] = make_float2(Ar, Ai);
                if (c == 0) featbf[((size_t)b * NF + ma) * FP + kp] = f2bf(sqrtf(Ar * Ar + Ai * Ai));
            }
            if (mb_ < NF) {
                X[((size_t)(b * NF + mb_) * CH + c) * FP + kp] = make_float2(Br, Bi);
                if (c == 0) featbf[((size_t)b * NF + mb_) * FP + kp] = f2bf(sqrtf(Br * Br + Bi * Bi));
            }
        }
    }
}

// ---------------- MLP layer via bf16 MFMA ----------------
template<int K, int ACT>
__global__ __launch_bounds__(256) void k_mfma_mlp(const unsigned short* __restrict__ Abf,
                                                  const unsigned short* __restrict__ Wt,
                                                  const float* __restrict__ bias,
                                                  float* __restrict__ outf,
                                                  unsigned short* __restrict__ outbf,
                                                  int M) {
    __shared__ unsigned short Al[64][40];
    __shared__ unsigned short Bl[128][40];
    int bid = blockIdx.x;
    int nt = bid & 3, mt = bid >> 2;
    int m0 = mt * 64, n0 = nt * 128;
    int tid = threadIdx.x;
    int wid = tid >> 6, lane = tid & 63;
    int wm = wid >> 1, wn = wid & 1;
    int lr = lane & 15, lk = (lane >> 4) * 8;

    f32x4 acc[2][4] = {};

    int arow = tid >> 2, ak = (tid & 3) * 8;
    for (int k0 = 0; k0 < K; k0 += 32) {
        int garow = m0 + arow; if (garow > M - 1) garow = M - 1;
        float4 av = *(const float4*)&Abf[(size_t)garow * K + k0 + ak];
        int s0 = tid, s1 = tid + 256;
        float4 bv0 = *(const float4*)&Wt[(size_t)(n0 + (s0 >> 2)) * K + k0 + (s0 & 3) * 8];
        float4 bv1 = *(const float4*)&Wt[(size_t)(n0 + (s1 >> 2)) * K + k0 + (s1 & 3) * 8];
        if (k0 > 0) __syncthreads();
        *(float4*)&Al[arow][ak] = av;
        *(float4*)&Bl[s0 >> 2][(s0 & 3) * 8] = bv0;
        *(float4*)&Bl[s1 >> 2][(s1 & 3) * 8] = bv1;
        __syncthreads();
        bf16x8 af[2], bfr[4];
        af[0] = *(const bf16x8*)&Al[wm * 32 + lr][lk];
        af[1] = *(const bf16x8*)&Al[wm * 32 + 16 + lr][lk];
        #pragma unroll
        for (int nf = 0; nf < 4; ++nf)
            bfr[nf] = *(const bf16x8*)&Bl[wn * 64 + nf * 16 + lr][lk];
        #pragma unroll
        for (int mf = 0; mf < 2; ++mf)
            #pragma unroll
            for (int nf = 0; nf < 4; ++nf)
                acc[mf][nf] = __builtin_amdgcn_mfma_f32_16x16x32_bf16(af[mf], bfr[nf], acc[mf][nf], 0, 0, 0);
    }

    int rbase = (lane >> 4) * 4;
    #pragma unroll
    for (int mf = 0; mf < 2; ++mf) {
        #pragma unroll
        for (int nf = 0; nf < 4; ++nf) {
            int n = n0 + wn * 64 + nf * 16 + lr;
            float bj = bias[n];
            #pragma unroll
            for (int r = 0; r < 4; ++r) {
                int m = m0 + wm * 32 + mf * 16 + rbase + r;
                if (m < M) {
                    float vv = acc[mf][nf][r] + bj;
                    if (ACT == 0) {
                        outbf[(size_t)m * HID + n] = f2bf(fmaxf(vv, 0.f));
                    } else {
                        outf[(size_t)m * HID + n] = 1.f / (1.f + expf(-vv));
                    }
                }
            }
        }
    }
}

// ---------------- covariance partials: grid (nc, ftile, b); runtime chunk length ----------------
__global__ __launch_bounds__(512) void k_cov(const float2* __restrict__ X,
                                             const float* __restrict__ mo,
                                             float2* __restrict__ part, int cck) {
    int nc = blockIdx.x, ftile = blockIdx.y, b = blockIdx.z;
    int tid = threadIdx.x;
    int c = tid >> 6;
    int ft = tid & 63;
    int f = ftile * 64 + ft;
    int n0 = nc * cck;
    int n1 = n0 + cck; if (n1 > NF) n1 = NF;

    __shared__ float2 vbuf[2][NSTG][CH][64];

    float ar[8], ai[8];
    #pragma unroll
    for (int d = 0; d < 8; ++d) { ar[d] = 0.f; ai[d] = 0.f; }
    float rr = 0.f, ri = 0.f;

    const float2* Xb = X + (size_t)b * NF * CH * FP;
    const float* mb = mo + (size_t)b * NF * HID;

    #pragma unroll
    for (int r = 0; r < NSTG; ++r) {
        int n = n0 + r;
        if (n < n1) vbuf[0][r][c][ft] = Xb[(size_t)(n * CH + c) * FP + f];
    }
    __syncthreads();
    int cur = 0;
    for (int nb = n0; nb < n1; nb += NSTG) {
        int nbn = nb + NSTG;
        float2 nx[NSTG];
        #pragma unroll
        for (int r = 0; r < NSTG; ++r) {
            int n = nbn + r;
            if (n < n1) nx[r] = Xb[(size_t)(n * CH + c) * FP + f];
        }
        float mts[NSTG], mns[NSTG];
        #pragma unroll
        for (int r = 0; r < NSTG; ++r) {
            int n = nb + r;
            if (n < n1) {
                mts[r] = mb[(size_t)n * HID + f];
                mns[r] = mb[(size_t)n * HID + FP + f];
            }
        }
        #pragma unroll
        for (int r = 0; r < NSTG; ++r) {
            int n = nb + r;
            if (n < n1) {
                float mt = mts[r], mn = mns[r];
                float w = mt + mn;
                float2 xc = vbuf[cur][r][c][ft];
                #pragma unroll
                for (int d = 0; d < 8; ++d) {
                    float2 xd = vbuf[cur][r][d][ft];
                    float pr = xc.x * xd.x + xc.y * xd.y;
                    float pi = xc.y * xd.x - xc.x * xd.y;
                    ar[d] += w * pr; ai[d] += w * pi;
                    if (d == 0) { rr += mt * pr; ri += mt * pi; }
                }
            }
        }
        if (nbn < n1) {
            #pragma unroll
            for (int r = 0; r < NSTG; ++r) {
                int n = nbn + r;
                if (n < n1) vbuf[cur ^ 1][r][c][ft] = nx[r];
            }
        }
        __syncthreads();
        cur ^= 1;
    }
    float2* pp = part + (((size_t)nc * BATCH + b) * FP + f) * 72;
    #pragma unroll
    for (int d = 0; d < 8; ++d)
        pp[c * 8 + d] = make_float2(ar[d], ai[d]);
    pp[64 + c] = make_float2(rr, ri);
}

// ---------------- reduce partials + 8x8 complex solve ----------------
__global__ __launch_bounds__(512) void k_cov_solve2(const float2* __restrict__ part,
                                                    float2* __restrict__ wc, int ncnt) {
    int blk = blockIdx.x;
    int fg = blk & 31;
    int b = blk >> 5;
    int tid = threadIdx.x;
    int c = tid >> 6, d = (tid >> 3) & 7, fl = tid & 7;
    int f = fg * 8 + fl;
    float ar = 0.f, ai = 0.f, rr = 0.f, ri = 0.f;
    const float2* pb = part + ((size_t)b * FP + f) * 72;
    for (int nc = 0; nc < ncnt; ++nc) {
        const float2* p = pb + (size_t)nc * BATCH * FP * 72;
        float2 v = p[c * 8 + d];
        ar += v.x; ai += v.y;
        if (d == 0) { float2 u = p[64 + c]; rr += u.x; ri += u.y; }
    }
    __shared__ float2 Am[8][73];
    __shared__ float2 rh[8][8];
    __shared__ float2 sl[8][9];
    Am[fl][c * 9 + d] = make_float2(ar, ai);
    if (d == 0) rh[fl][c] = make_float2(rr, ri);
    __syncthreads();
    if (tid < 8) {
        int ln = tid;
        float2* A = Am[ln];
        float2* r = rh[ln];
        float2* sol = sl[ln];
        for (int kk = 0; kk < 8; ++kk) {
            float2 pp = A[kk * 9 + kk];
            float ip = 1.f / (pp.x * pp.x + pp.y * pp.y);
            float invr = pp.x * ip, invi = -pp.y * ip;
            for (int i = kk + 1; i < 8; ++i) {
                float2 aik = A[i * 9 + kk];
                float fr2 = aik.x * invr - aik.y * invi;
                float fi2 = aik.x * invi + aik.y * invr;
                for (int jj = kk; jj < 8; ++jj) {
                    float2 ak = A[kk * 9 + jj];
                    A[i * 9 + jj].x -= fr2 * ak.x - fi2 * ak.y;
                    A[i * 9 + jj].y -= fr2 * ak.y + fi2 * ak.x;
                }
                r[i].x -= fr2 * r[kk].x - fi2 * r[kk].y;
                r[i].y -= fr2 * r[kk].y + fi2 * r[kk].x;
            }
        }
        for (int kk = 7; kk >= 0; --kk) {
            float sr = r[kk].x, si = r[kk].y;
            for (int jj = kk + 1; jj < 8; ++jj) {
                float2 ak = A[kk * 9 + jj];
                float2 xj = sol[jj];
                sr -= ak.x * xj.x - ak.y * xj.y;
                si -= ak.x * xj.y + ak.y * xj.x;
            }
            float2 pp = A[kk * 9 + kk];
            float ip = 1.f / (pp.x * pp.x + pp.y * pp.y);
            sol[kk].x = (sr * pp.x + si * pp.y) * ip;
            sol[kk].y = (si * pp.x - sr * pp.y) * ip;
        }
        for (int cc = 0; cc < 8; ++cc)
            wc[((size_t)b * CH + cc) * FP + fg * 8 + ln] = make_float2(sol[cc].x, -sol[cc].y);
    }
}

// ---------------- fused beamform + ISTFT ----------------
__global__ __launch_bounds__(512) void k_istft_bf(const float2* __restrict__ X,
                                                  const float2* __restrict__ wc,
                                                  float* __restrict__ yfr) {
    __shared__ float2 Zp[4 * 512];
    __shared__ float2 Gl[16 * 32 * 5];
    int blk = blockIdx.x;
    int g = blk % NGRP, b = blk / NGRP;
    int m0 = g * FPB;
    int tid = threadIdx.x;

    if (tid < 4) Zp[tid * 512] = make_float2(0.f, 0.f);
    const float2* Xb0 = X + (size_t)b * NF * CH * FP;
    const float2* wcb = wc + (size_t)b * CH * FP;
    #pragma unroll
    for (int half = 0; half < 2; ++half) {
        int i = half * 512 + tid;
        int sig = i >> 8, kp = i & 255;
        int ma = m0 + 2 * sig, mb_ = ma + 1;
        float2 Xa = make_float2(0.f, 0.f), Xb = make_float2(0.f, 0.f);
        if (ma < NF) {
            #pragma unroll
            for (int c = 0; c < 8; ++c) {
                float2 xv = Xb0[(size_t)(ma * CH + c) * FP + kp];
                float2 wv = wcb[c * FP + kp];
                Xa.x += xv.x * wv.x - xv.y * wv.y;
                Xa.y += xv.x * wv.y + xv.y * wv.x;
            }
        }
        if (mb_ < NF) {
            #pragma unroll
            for (int c = 0; c < 8; ++c) {
                float2 xv = Xb0[(size_t)(mb_ * CH + c) * FP + kp];
                float2 wv = wcb[c * FP + kp];
                Xb.x += xv.x * wv.x - xv.y * wv.y;
                Xb.y += xv.x * wv.y + xv.y * wv.x;
            }
        }
        int k = kp + 1;
        if (k == 256) {
            Zp[sig * 512 + 256] = make_float2(Xa.x, Xb.x);
        } else {
            Zp[sig * 512 + k]       = make_float2(Xa.x - Xb.y, Xa.y + Xb.x);
            Zp[sig * 512 + 512 - k] = make_float2(Xa.x + Xb.y, Xb.x - Xa.y);
        }
    }
    __syncthreads();

    {
        int k1 = tid >> 5, tau = tid & 31;
        float sa, ca;
        sincosf((float)tau * (float)(2.0 * M_PI / 32.0), &sa, &ca);
        float stepc = ca, steps = sa;
        float gr[4], gi[4];
        #pragma unroll
        for (int s = 0; s < 4; ++s) { gr[s] = 0.f; gi[s] = 0.f; }
        float cr = 1.f, ci = 0.f;
        #pragma unroll 4
        for (int k2 = 0; k2 < 32; ++k2) {
            int k = k1 + 16 * k2;
            #pragma unroll
            for (int s = 0; s < 4; ++s) {
                float2 z = Zp[s * 512 + k];
                gr[s] += z.x * cr - z.y * ci;
                gi[s] += z.x * ci + z.y * cr;
            }
            float ncr = cr * stepc - ci * steps;
            ci = cr * steps + ci * stepc;
            cr = ncr;
        }
        #pragma unroll
        for (int s = 0; s < 4; ++s)
            Gl[(k1 * 32 + tau) * 5 + s] = make_float2(gr[s], gi[s]);
    }
    __syncthreads();

    int t = tid;
    int tau = t & 31;
    float sa2, ca2;
    sincosf((float)t * (float)(2.0 * M_PI / 512.0), &sa2, &ca2);
    float stepc = ca2, steps = sa2;
    float accr[4], acci[4];
    #pragma unroll
    for (int s = 0; s < 4; ++s) { accr[s] = 0.f; acci[s] = 0.f; }
    float cr = 1.f, ci = 0.f;
    #pragma unroll 4
    for (int k1 = 0; k1 < 16; ++k1) {
        #pragma unroll
        for (int s = 0; s < 4; ++s) {
            float2 gv = Gl[(k1 * 32 + tau) * 5 + s];
            accr[s] += gv.x * cr - gv.y * ci;
            acci[s] += gv.x * ci + gv.y * cr;
        }
        float ncr = cr * stepc - ci * steps;
        ci = cr * steps + ci * stepc;
        cr = ncr;
    }
    float wv = (0.5f - 0.5f * ca2) * (1.f / 512.f);
    #pragma unroll
    for (int s = 0; s < 4; ++s) {
        int ma = m0 + 2 * s, mb_ = ma + 1;
        if (ma < NF)  yfr[((size_t)b * NFP + ma) * 512 + t] = accr[s] * wv;
        if (mb_ < NF) yfr[((size_t)b * NFP + mb_) * 512 + t] = acci[s] * wv;
    }
}

// ---------------- gather overlap-add + wsum normalize ----------------
__global__ __launch_bounds__(256) void k_out(const float* __restrict__ yfr,
                                             float* __restrict__ out) {
    int i = blockIdx.x * blockDim.x + threadIdx.x;
    if (i >= BATCH * TLEN) return;
    int b = i / TLEN;
    int t = i - b * TLEN;
    int p = t + PADW;
    int q = p & 127;
    int m0 = p >> 7;
    float sq, cq;
    sincosf((float)q * (float)(2.0 * M_PI / 512.0), &sq, &cq);
    float w4[4] = {0.5f - 0.5f * cq, 0.5f + 0.5f * sq, 0.5f + 0.5f * cq, 0.5f - 0.5f * sq};
    float val = 0.f, wsum = 0.f;
    const float* yb = yfr + (size_t)b * NFP * 512;
    #pragma unroll
    for (int dm = 0; dm < 4; ++dm) {
        int mm = m0 - dm;
        if (mm >= 0 && mm < NF) {
            val += yb[(size_t)mm * 512 + q + 128 * dm];
            wsum += w4[dm] * w4[dm];
        }
    }
    out[i] = val / fmaxf(wsum, 1e-10f);
}

extern "C" void kernel_launch(void* const* d_in, const int* in_sizes, int n_in,
                              void* d_out, int out_size, void* d_ws, size_t ws_size,
                              hipStream_t stream) {
    const float* x  = (const float*)d_in[0];
    const float* w1 = (const float*)d_in[1];
    const float* b1 = (const float*)d_in[2];
    const float* w2 = (const float*)d_in[3];
    const float* b2 = (const float*)d_in[4];

    float* ws = (float*)d_ws;
    size_t off = 0;
    float*  tw    = ws + off; off += 512;
    float2* X     = (float2*)(ws + off); off += (size_t)BATCH * FP * NF * CH * 2;
    float*  mo    = ws + off; off += (size_t)BATCH * NF * HID;
    float2* wc    = (float2*)(ws + off); off += (size_t)BATCH * FP * CH * 2;
    float*  yfr   = ws + off; off += (size_t)BATCH * NFP * 512;
    unsigned short* featbf = (unsigned short*)(ws + off); off += (size_t)MROWS * FP / 2;
    unsigned short* hbf    = (unsigned short*)(ws + off); off += (size_t)MROWS * HID / 2;
    unsigned short* wt1bf  = (unsigned short*)(ws + off); off += (size_t)HID * FP / 2;
    unsigned short* wt2bf  = (unsigned short*)(ws + off); off += (size_t)HID * HID / 2;
    float2* part  = (float2*)(ws + off);   // runtime-sized, last

    // choose cov n-chunk count by available workspace (deterministic: depends only on ws_size)
    int cnck = 8, cck = 63;
    size_t need16 = (off + (size_t)16 * BATCH * FP * 72 * 2) * sizeof(float);
    if (ws_size >= need16) { cnck = 16; cck = 32; }

    k_prep<<<385, 256, 0, stream>>>(w1, w2, tw, wt1bf, wt2bf);
    k_stft<<<BATCH * CH * NGRP, 256, 0, stream>>>(x, tw, X, featbf);
    k_mfma_mlp<FP, 0><<<63 * 4, 256, 0, stream>>>(featbf, wt1bf, b1, mo, hbf, MROWS);
    k_mfma_mlp<HID, 1><<<63 * 4, 256, 0, stream>>>(hbf, wt2bf, b2, mo, hbf, MROWS);
    k_cov<<<dim3(cnck, 4, BATCH), 512, 0, stream>>>(X, mo, part, cck);
    k_cov_solve2<<<BATCH * 32, 512, 0, stream>>>(part, wc, cnck);
    k_istft_bf<<<BATCH * NGRP, 512, 0, stream>>>(X, wc, yfr);
    k_out<<<(BATCH * TLEN + 255) / 256, 256, 0, stream>>>(yfr, (float*)d_out);
}

// Round 13
// 123.422 us; speedup vs baseline: 1.4817x; 1.0022x over previous
//
#include <hip/hip_runtime.h>
#include <hip/hip_bf16.h>
#include <math.h>

#define NFFT 512
#define HOP  128
#define PADW 256
#define TLEN 64000
#define NF   501
#define NFP  504
#define FP   256
#define CH   8
#define BATCH 8
#define HID  512
#define MROWS (BATCH * NF)   // 4008
#define FPB  8
#define NGRP 63
#define NSTG 4

#define S2C 0.70710678118654752f

typedef short bf16x8 __attribute__((ext_vector_type(8)));
typedef float f32x4 __attribute__((ext_vector_type(4)));

__device__ __forceinline__ unsigned short f2bf(float v) {
    __hip_bfloat16 hb = __float2bfloat16(v);
    return *reinterpret_cast<unsigned short*>(&hb);
}
__device__ __forceinline__ float bf2f(unsigned short u) {
    unsigned int t = ((unsigned int)u) << 16;
    float f;
    __builtin_memcpy(&f, &t, 4);
    return f;
}
__device__ __forceinline__ float2 bf2c(ushort2 v) { return make_float2(bf2f(v.x), bf2f(v.y)); }
__device__ __forceinline__ ushort2 c2bf(float2 v) { ushort2 o; o.x = f2bf(v.x); o.y = f2bf(v.y); return o; }

// ---------------- complex helpers ----------------
__device__ __forceinline__ float2 cadd(float2 a, float2 b) { return make_float2(a.x + b.x, a.y + b.y); }
__device__ __forceinline__ float2 csub(float2 a, float2 b) { return make_float2(a.x - b.x, a.y - b.y); }
__device__ __forceinline__ float2 cmul(float2 a, float2 b) { return make_float2(a.x * b.x - a.y * b.y, a.x * b.y + a.y * b.x); }
__device__ __forceinline__ float2 mulnegi(float2 a) { return make_float2(a.y, -a.x); }

__device__ __forceinline__ void dft8(const float2 u[8], float2 v[8]) {
    float2 a0 = cadd(u[0], u[4]), a1 = cadd(u[1], u[5]), a2 = cadd(u[2], u[6]), a3 = cadd(u[3], u[7]);
    float2 b0 = csub(u[0], u[4]), b1 = csub(u[1], u[5]), b2 = csub(u[2], u[6]), b3 = csub(u[3], u[7]);
    float2 c0 = cadd(a0, a2), c1 = csub(a0, a2), c2 = cadd(a1, a3), c3 = csub(a1, a3);
    v[0] = cadd(c0, c2); v[4] = csub(c0, c2);
    float2 nic3 = mulnegi(c3);
    v[2] = cadd(c1, nic3); v[6] = csub(c1, nic3);
    float2 d1 = make_float2(S2C * (b1.x + b1.y), S2C * (b1.y - b1.x));
    float2 d2 = mulnegi(b2);
    float2 d3 = make_float2(S2C * (b3.y - b3.x), -S2C * (b3.x + b3.y));
    float2 e0 = cadd(b0, d2), e1 = csub(b0, d2), e2 = cadd(d1, d3), e3 = csub(d1, d3);
    v[1] = cadd(e0, e2); v[5] = csub(e0, e2);
    float2 nie3 = mulnegi(e3);
    v[3] = cadd(e1, nie3); v[7] = csub(e1, nie3);
}

__device__ __forceinline__ int refl(int j) {
    j = (j < 0) ? -j : j;
    j = (j >= TLEN) ? 2 * (TLEN - 1) - j : j;
    return j;
}

// ---------------- prep: hann table + both weight transposes (1 launch) ----------------
__global__ __launch_bounds__(256) void k_prep(const float* __restrict__ w1,
                                              const float* __restrict__ w2,
                                              float* __restrict__ tw,
                                              unsigned short* __restrict__ wt1,
                                              unsigned short* __restrict__ wt2) {
    __shared__ float tile[32][33];
    int bid = blockIdx.x;
    if (bid == 384) {
        #pragma unroll
        for (int r = 0; r < 2; ++r) {
            int e = threadIdx.x + 256 * r;
            float ang = (float)(2.0 * M_PI * (double)e / 512.0);
            tw[e] = 0.5f - 0.5f * cosf(ang);
        }
        return;
    }
    const float* w; unsigned short* wt; int K, lb;
    if (bid < 128) { w = w1; wt = wt1; K = 256; lb = bid; }
    else           { w = w2; wt = wt2; K = 512; lb = bid - 128; }
    int nt = lb & 15, kt = lb >> 4;
    int tx = threadIdx.x & 31, ty = threadIdx.x >> 5;
    #pragma unroll
    for (int r = 0; r < 4; ++r)
        tile[ty + 8 * r][tx] = w[(size_t)(kt * 32 + ty + 8 * r) * HID + nt * 32 + tx];
    __syncthreads();
    #pragma unroll
    for (int r = 0; r < 4; ++r)
        wt[(size_t)(nt * 32 + ty + 8 * r) * K + kt * 32 + tx] = f2bf(tile[tx][ty + 8 * r]);
}

// ---------------- STFT: radix-8^3 Stockham FFT on frame-pairs; X stored bf16 ----------------
#define A_S 580
#define B_S 544
__global__ __launch_bounds__(256, 4) void k_stft(const float* __restrict__ x,
                                                 const float* __restrict__ tw,
                                                 ushort2* __restrict__ X,
                                                 unsigned short* __restrict__ featbf) {
    __shared__ float2 Abuf[4 * A_S];
    __shared__ float2 Bbuf[4 * B_S];
    __shared__ float2 Twd[512];
    int blk = blockIdx.x;
    int g = blk % NGRP;
    int bc = blk / NGRP;
    int c = bc % CH, b = bc / CH;
    int m0 = g * FPB;
    int tid = threadIdx.x;
    const float* xp = x + (size_t)(b * CH + c) * TLEN;

    #pragma unroll
    for (int r = 0; r < 2; ++r) {
        int e = tid + 256 * r;
        float se, ce;
        sincosf((float)e * (float)(2.0 * M_PI / 512.0), &se, &ce);
        Twd[e] = make_float2(ce, -se);
    }

    // stage the 1536-sample span once (Bbuf as scratch)
    float* xs = (float*)Bbuf;
    int base = m0 * HOP - PADW;
    #pragma unroll
    for (int r = 0; r < 6; ++r) {
        int i = r * 256 + tid;
        xs[i] = xp[refl(base + i)];
    }
    __syncthreads();

    #pragma unroll
    for (int r = 0; r < 8; ++r) {
        int flat = r * 256 + tid;
        int sig = flat >> 9, t = flat & 511;
        float w = tw[t];
        Abuf[sig * A_S + t] = make_float2(xs[2 * sig * 128 + t] * w,
                                          xs[(2 * sig + 1) * 128 + t] * w);
    }
    __syncthreads();

    int sig = tid >> 6, dft = tid & 63;
    float2 u[8], v[8];

    // stage 1
    {
        const float2* Az = &Abuf[sig * A_S];
        float2* Bu = &Bbuf[sig * B_S];
        #pragma unroll
        for (int a = 0; a < 8; ++a) u[a] = Az[64 * a + dft];
        dft8(u, v);
        #pragma unroll
        for (int k0 = 0; k0 < 8; ++k0) Bu[k0 * 68 + dft] = v[k0];
    }
    __syncthreads();

    // stage 2
    {
        int k0 = dft >> 3, cd = dft & 7;
        const float2* Bu = &Bbuf[sig * B_S];
        float2* Au = &Abuf[sig * A_S];
        #pragma unroll
        for (int bb = 0; bb < 8; ++bb) u[bb] = Bu[k0 * 68 + 8 * bb + cd];
        #pragma unroll
        for (int bb = 1; bb < 8; ++bb) u[bb] = cmul(u[bb], Twd[(8 * bb * k0) & 511]);
        dft8(u, v);
        #pragma unroll
        for (int k1 = 0; k1 < 8; ++k1) Au[(8 * k0 + k1) * 9 + cd] = v[k1];
    }
    __syncthreads();

    // stage 3
    {
        int k0 = dft >> 3, k1 = dft & 7;
        int kk = k0 + 8 * k1;
        const float2* Au = &Abuf[sig * A_S];
        float2* Bz = &Bbuf[sig * B_S];
        #pragma unroll
        for (int cd = 0; cd < 8; ++cd) u[cd] = Au[dft * 9 + cd];
        #pragma unroll
        for (int cd = 1; cd < 8; ++cd) u[cd] = cmul(u[cd], Twd[(cd * kk) & 511]);
        dft8(u, v);
        #pragma unroll
        for (int k2 = 0; k2 < 8; ++k2) Bz[kk + 64 * k2] = v[k2];
    }
    __syncthreads();

    // Hermitian unpack -> bf16 X
    {
        int kp = tid;
        int k = kp + 1;
        #pragma unroll
        for (int s = 0; s < 4; ++s) {
            float2 z1 = Bbuf[s * B_S + k];
            float2 z2 = Bbuf[s * B_S + (512 - k)];
            float Ar = 0.5f * (z1.x + z2.x);
            float Ai = 0.5f * (z1.y - z2.y);
            float Br = 0.5f * (z1.y + z2.y);
            float Bi = 0.5f * (z2.x - z1.x);
            int ma = m0 + 2 * s, mb_ = ma + 1;
            if (ma < NF) {
                X[((size_t)(b * NF + ma) * CH + c) * FP + kp] = c2bf(make_float2(Ar, Ai));
                if (c == 0) featbf[((size_t)b * NF + ma) * FP + kp] = f2bf(sqrtf(Ar * Ar + Ai * Ai));
            }
            if (mb_ < NF) {
                X[((size_t)(b * NF + mb_) * CH + c) * FP + kp] = c2bf(make_float2(Br, Bi));
                if (c == 0) featbf[((size_t)b * NF + mb_) * FP + kp] = f2bf(sqrtf(Br * Br + Bi * Bi));
            }
        }
    }
}

// ---------------- MLP layer via bf16 MFMA (both layers emit bf16) ----------------
template<int K, int ACT>
__global__ __launch_bounds__(256) void k_mfma_mlp(const unsigned short* __restrict__ Abf,
                                                  const unsigned short* __restrict__ Wt,
                                                  const float* __restrict__ bias,
                                                  unsigned short* __restrict__ outbf,
                                                  int M) {
    __shared__ unsigned short Al[64][40];
    __shared__ unsigned short Bl[128][40];
    int bid = blockIdx.x;
    int nt = bid & 3, mt = bid >> 2;
    int m0 = mt * 64, n0 = nt * 128;
    int tid = threadIdx.x;
    int wid = tid >> 6, lane = tid & 63;
    int wm = wid >> 1, wn = wid & 1;
    int lr = lane & 15, lk = (lane >> 4) * 8;

    f32x4 acc[2][4] = {};

    int arow = tid >> 2, ak = (tid & 3) * 8;
    for (int k0 = 0; k0 < K; k0 += 32) {
        int garow = m0 + arow; if (garow > M - 1) garow = M - 1;
        float4 av = *(const float4*)&Abf[(size_t)garow * K + k0 + ak];
        int s0 = tid, s1 = tid + 256;
        float4 bv0 = *(const float4*)&Wt[(size_t)(n0 + (s0 >> 2)) * K + k0 + (s0 & 3) * 8];
        float4 bv1 = *(const float4*)&Wt[(size_t)(n0 + (s1 >> 2)) * K + k0 + (s1 & 3) * 8];
        if (k0 > 0) __syncthreads();
        *(float4*)&Al[arow][ak] = av;
        *(float4*)&Bl[s0 >> 2][(s0 & 3) * 8] = bv0;
        *(float4*)&Bl[s1 >> 2][(s1 & 3) * 8] = bv1;
        __syncthreads();
        bf16x8 af[2], bfr[4];
        af[0] = *(const bf16x8*)&Al[wm * 32 + lr][lk];
        af[1] = *(const bf16x8*)&Al[wm * 32 + 16 + lr][lk];
        #pragma unroll
        for (int nf = 0; nf < 4; ++nf)
            bfr[nf] = *(const bf16x8*)&Bl[wn * 64 + nf * 16 + lr][lk];
        #pragma unroll
        for (int mf = 0; mf < 2; ++mf)
            #pragma unroll
            for (int nf = 0; nf < 4; ++nf)
                acc[mf][nf] = __builtin_amdgcn_mfma_f32_16x16x32_bf16(af[mf], bfr[nf], acc[mf][nf], 0, 0, 0);
    }

    int rbase = (lane >> 4) * 4;
    #pragma unroll
    for (int mf = 0; mf < 2; ++mf) {
        #pragma unroll
        for (int nf = 0; nf < 4; ++nf) {
            int n = n0 + wn * 64 + nf * 16 + lr;
            float bj = bias[n];
            #pragma unroll
            for (int r = 0; r < 4; ++r) {
                int m = m0 + wm * 32 + mf * 16 + rbase + r;
                if (m < M) {
                    float vv = acc[mf][nf][r] + bj;
                    float o = (ACT == 0) ? fmaxf(vv, 0.f) : 1.f / (1.f + expf(-vv));
                    outbf[(size_t)m * HID + n] = f2bf(o);
                }
            }
        }
    }
}

// ---------------- covariance partials: bf16 X/mask in, fp32 accumulate ----------------
__global__ __launch_bounds__(512) void k_cov(const ushort2* __restrict__ X,
                                             const unsigned short* __restrict__ mo,
                                             float2* __restrict__ part, int cck) {
    int nc = blockIdx.x, ftile = blockIdx.y, b = blockIdx.z;
    int tid = threadIdx.x;
    int c = tid >> 6;
    int ft = tid & 63;
    int f = ftile * 64 + ft;
    int n0 = nc * cck;
    int n1 = n0 + cck; if (n1 > NF) n1 = NF;

    __shared__ float2 vbuf[2][NSTG][CH][64];

    float ar[8], ai[8];
    #pragma unroll
    for (int d = 0; d < 8; ++d) { ar[d] = 0.f; ai[d] = 0.f; }
    float rr = 0.f, ri = 0.f;

    const ushort2* Xb = X + (size_t)b * NF * CH * FP;
    const unsigned short* mb = mo + (size_t)b * NF * HID;

    #pragma unroll
    for (int r = 0; r < NSTG; ++r) {
        int n = n0 + r;
        if (n < n1) vbuf[0][r][c][ft] = bf2c(Xb[(size_t)(n * CH + c) * FP + f]);
    }
    __syncthreads();
    int cur = 0;
    for (int nb = n0; nb < n1; nb += NSTG) {
        int nbn = nb + NSTG;
        ushort2 nx[NSTG];
        #pragma unroll
        for (int r = 0; r < NSTG; ++r) {
            int n = nbn + r;
            if (n < n1) nx[r] = Xb[(size_t)(n * CH + c) * FP + f];
        }
        float mts[NSTG], mns[NSTG];
        #pragma unroll
        for (int r = 0; r < NSTG; ++r) {
            int n = nb + r;
            if (n < n1) {
                mts[r] = bf2f(mb[(size_t)n * HID + f]);
                mns[r] = bf2f(mb[(size_t)n * HID + FP + f]);
            }
        }
        #pragma unroll
        for (int r = 0; r < NSTG; ++r) {
            int n = nb + r;
            if (n < n1) {
                float mt = mts[r], mn = mns[r];
                float w = mt + mn;
                float2 xc = vbuf[cur][r][c][ft];
                #pragma unroll
                for (int d = 0; d < 8; ++d) {
                    float2 xd = vbuf[cur][r][d][ft];
                    float pr = xc.x * xd.x + xc.y * xd.y;
                    float pi = xc.y * xd.x - xc.x * xd.y;
                    ar[d] += w * pr; ai[d] += w * pi;
                    if (d == 0) { rr += mt * pr; ri += mt * pi; }
                }
            }
        }
        if (nbn < n1) {
            #pragma unroll
            for (int r = 0; r < NSTG; ++r) {
                int n = nbn + r;
                if (n < n1) vbuf[cur ^ 1][r][c][ft] = bf2c(nx[r]);
            }
        }
        __syncthreads();
        cur ^= 1;
    }
    float2* pp = part + (((size_t)nc * BATCH + b) * FP + f) * 72;
    #pragma unroll
    for (int d = 0; d < 8; ++d)
        pp[c * 8 + d] = make_float2(ar[d], ai[d]);
    pp[64 + c] = make_float2(rr, ri);
}

// ---------------- reduce partials + 8x8 complex solve ----------------
__global__ __launch_bounds__(512) void k_cov_solve2(const float2* __restrict__ part,
                                                    float2* __restrict__ wc, int ncnt) {
    int blk = blockIdx.x;
    int fg = blk & 31;
    int b = blk >> 5;
    int tid = threadIdx.x;
    int c = tid >> 6, d = (tid >> 3) & 7, fl = tid & 7;
    int f = fg * 8 + fl;
    float ar = 0.f, ai = 0.f, rr = 0.f, ri = 0.f;
    const float2* pb = part + ((size_t)b * FP + f) * 72;
    for (int nc = 0; nc < ncnt; ++nc) {
        const float2* p = pb + (size_t)nc * BATCH * FP * 72;
        float2 v = p[c * 8 + d];
        ar += v.x; ai += v.y;
        if (d == 0) { float2 u = p[64 + c]; rr += u.x; ri += u.y; }
    }
    __shared__ float2 Am[8][73];
    __shared__ float2 rh[8][8];
    __shared__ float2 sl[8][9];
    Am[fl][c * 9 + d] = make_float2(ar, ai);
    if (d == 0) rh[fl][c] = make_float2(rr, ri);
    __syncthreads();
    if (tid < 8) {
        int ln = tid;
        float2* A = Am[ln];
        float2* r = rh[ln];
        float2* sol = sl[ln];
        for (int kk = 0; kk < 8; ++kk) {
            float2 pp = A[kk * 9 + kk];
            float ip = 1.f / (pp.x * pp.x + pp.y * pp.y);
            float invr = pp.x * ip, invi = -pp.y * ip;
            for (int i = kk + 1; i < 8; ++i) {
                float2 aik = A[i * 9 + kk];
                float fr2 = aik.x * invr - aik.y * invi;
                float fi2 = aik.x * invi + aik.y * invr;
                for (int jj = kk; jj < 8; ++jj) {
                    float2 ak = A[kk * 9 + jj];
                    A[i * 9 + jj].x -= fr2 * ak.x - fi2 * ak.y;
                    A[i * 9 + jj].y -= fr2 * ak.y + fi2 * ak.x;
                }
                r[i].x -= fr2 * r[kk].x - fi2 * r[kk].y;
                r[i].y -= fr2 * r[kk].y + fi2 * r[kk].x;
            }
        }
        for (int kk = 7; kk >= 0; --kk) {
            float sr = r[kk].x, si = r[kk].y;
            for (int jj = kk + 1; jj < 8; ++jj) {
                float2 ak = A[kk * 9 + jj];
                float2 xj = sol[jj];
                sr -= ak.x * xj.x - ak.y * xj.y;
                si -= ak.x * xj.y + ak.y * xj.x;
            }
            float2 pp = A[kk * 9 + kk];
            float ip = 1.f / (pp.x * pp.x + pp.y * pp.y);
            sol[kk].x = (sr * pp.x + si * pp.y) * ip;
            sol[kk].y = (si * pp.x - sr * pp.y) * ip;
        }
        for (int cc = 0; cc < 8; ++cc)
            wc[((size_t)b * CH + cc) * FP + fg * 8 + ln] = make_float2(sol[cc].x, -sol[cc].y);
    }
}

// ---------------- fused beamform + ISTFT (bf16 X in) ----------------
__global__ __launch_bounds__(512) void k_istft_bf(const ushort2* __restrict__ X,
                                                  const float2* __restrict__ wc,
                                                  float* __restrict__ yfr) {
    __shared__ float2 Zp[4 * 512];
    __shared__ float2 Gl[16 * 32 * 5];
    int blk = blockIdx.x;
    int g = blk % NGRP, b = blk / NGRP;
    int m0 = g * FPB;
    int tid = threadIdx.x;

    if (tid < 4) Zp[tid * 512] = make_float2(0.f, 0.f);
    const ushort2* Xb0 = X + (size_t)b * NF * CH * FP;
    const float2* wcb = wc + (size_t)b * CH * FP;
    #pragma unroll
    for (int half = 0; half < 2; ++half) {
        int i = half * 512 + tid;
        int sig = i >> 8, kp = i & 255;
        int ma = m0 + 2 * sig, mb_ = ma + 1;
        float2 Xa = make_float2(0.f, 0.f), Xb = make_float2(0.f, 0.f);
        if (ma < NF) {
            #pragma unroll
            for (int c = 0; c < 8; ++c) {
                float2 xv = bf2c(Xb0[(size_t)(ma * CH + c) * FP + kp]);
                float2 wv = wcb[c * FP + kp];
                Xa.x += xv.x * wv.x - xv.y * wv.y;
                Xa.y += xv.x * wv.y + xv.y * wv.x;
            }
        }
        if (mb_ < NF) {
            #pragma unroll
            for (int c = 0; c < 8; ++c) {
                float2 xv = bf2c(Xb0[(size_t)(mb_ * CH + c) * FP + kp]);
                float2 wv = wcb[c * FP + kp];
                Xb.x += xv.x * wv.x - xv.y * wv.y;
                Xb.y += xv.x * wv.y + xv.y * wv.x;
            }
        }
        int k = kp + 1;
        if (k == 256) {
            Zp[sig * 512 + 256] = make_float2(Xa.x, Xb.x);
        } else {
            Zp[sig * 512 + k]       = make_float2(Xa.x - Xb.y, Xa.y + Xb.x);
            Zp[sig * 512 + 512 - k] = make_float2(Xa.x + Xb.y, Xb.x - Xa.y);
        }
    }
    __syncthreads();

    {
        int k1 = tid >> 5, tau = tid & 31;
        float sa, ca;
        sincosf((float)tau * (float)(2.0 * M_PI / 32.0), &sa, &ca);
        float stepc = ca, steps = sa;
        float gr[4], gi[4];
        #pragma unroll
        for (int s = 0; s < 4; ++s) { gr[s] = 0.f; gi[s] = 0.f; }
        float cr = 1.f, ci = 0.f;
        #pragma unroll 4
        for (int k2 = 0; k2 < 32; ++k2) {
            int k = k1 + 16 * k2;
            #pragma unroll
            for (int s = 0; s < 4; ++s) {
                float2 z = Zp[s * 512 + k];
                gr[s] += z.x * cr - z.y * ci;
                gi[s] += z.x * ci + z.y * cr;
            }
            float ncr = cr * stepc - ci * steps;
            ci = cr * steps + ci * stepc;
            cr = ncr;
        }
        #pragma unroll
        for (int s = 0; s < 4; ++s)
            Gl[(k1 * 32 + tau) * 5 + s] = make_float2(gr[s], gi[s]);
    }
    __syncthreads();

    int t = tid;
    int tau = t & 31;
    float sa2, ca2;
    sincosf((float)t * (float)(2.0 * M_PI / 512.0), &sa2, &ca2);
    float stepc = ca2, steps = sa2;
    float accr[4], acci[4];
    #pragma unroll
    for (int s = 0; s < 4; ++s) { accr[s] = 0.f; acci[s] = 0.f; }
    float cr = 1.f, ci = 0.f;
    #pragma unroll 4
    for (int k1 = 0; k1 < 16; ++k1) {
        #pragma unroll
        for (int s = 0; s < 4; ++s) {
            float2 gv = Gl[(k1 * 32 + tau) * 5 + s];
            accr[s] += gv.x * cr - gv.y * ci;
            acci[s] += gv.x * ci + gv.y * cr;
        }
        float ncr = cr * stepc - ci * steps;
        ci = cr * steps + ci * stepc;
        cr = ncr;
    }
    float wv = (0.5f - 0.5f * ca2) * (1.f / 512.f);
    #pragma unroll
    for (int s = 0; s < 4; ++s) {
        int ma = m0 + 2 * s, mb_ = ma + 1;
        if (ma < NF)  yfr[((size_t)b * NFP + ma) * 512 + t] = accr[s] * wv;
        if (mb_ < NF) yfr[((size_t)b * NFP + mb_) * 512 + t] = acci[s] * wv;
    }
}

// ---------------- gather overlap-add + wsum normalize ----------------
__global__ __launch_bounds__(256) void k_out(const float* __restrict__ yfr,
                                             float* __restrict__ out) {
    int i = blockIdx.x * blockDim.x + threadIdx.x;
    if (i >= BATCH * TLEN) return;
    int b = i / TLEN;
    int t = i - b * TLEN;
    int p = t + PADW;
    int q = p & 127;
    int m0 = p >> 7;
    float sq, cq;
    sincosf((float)q * (float)(2.0 * M_PI / 512.0), &sq, &cq);
    float w4[4] = {0.5f - 0.5f * cq, 0.5f + 0.5f * sq, 0.5f + 0.5f * cq, 0.5f - 0.5f * sq};
    float val = 0.f, wsum = 0.f;
    const float* yb = yfr + (size_t)b * NFP * 512;
    #pragma unroll
    for (int dm = 0; dm < 4; ++dm) {
        int mm = m0 - dm;
        if (mm >= 0 && mm < NF) {
            val += yb[(size_t)mm * 512 + q + 128 * dm];
            wsum += w4[dm] * w4[dm];
        }
    }
    out[i] = val / fmaxf(wsum, 1e-10f);
}

extern "C" void kernel_launch(void* const* d_in, const int* in_sizes, int n_in,
                              void* d_out, int out_size, void* d_ws, size_t ws_size,
                              hipStream_t stream) {
    const float* x  = (const float*)d_in[0];
    const float* w1 = (const float*)d_in[1];
    const float* b1 = (const float*)d_in[2];
    const float* w2 = (const float*)d_in[3];
    const float* b2 = (const float*)d_in[4];

    float* ws = (float*)d_ws;
    size_t off = 0;   // in floats (4B units)
    float*  tw    = ws + off; off += 512;
    ushort2* X    = (ushort2*)(ws + off); off += (size_t)BATCH * NF * CH * FP;   // 4B each
    float2* wc    = (float2*)(ws + off); off += (size_t)BATCH * FP * CH * 2;
    float*  yfr   = ws + off; off += (size_t)BATCH * NFP * 512;
    unsigned short* featbf = (unsigned short*)(ws + off); off += (size_t)MROWS * FP / 2;
    unsigned short* hbf    = (unsigned short*)(ws + off); off += (size_t)MROWS * HID / 2;
    unsigned short* mobf   = (unsigned short*)(ws + off); off += (size_t)MROWS * HID / 2;
    unsigned short* wt1bf  = (unsigned short*)(ws + off); off += (size_t)HID * FP / 2;
    unsigned short* wt2bf  = (unsigned short*)(ws + off); off += (size_t)HID * HID / 2;
    float2* part  = (float2*)(ws + off);   // runtime-sized, last

    int cnck = 8, cck = 63;
    size_t need16 = (off + (size_t)16 * BATCH * FP * 72 * 4) * sizeof(float);
    if (ws_size >= need16) { cnck = 16; cck = 32; }

    k_prep<<<385, 256, 0, stream>>>(w1, w2, tw, wt1bf, wt2bf);
    k_stft<<<BATCH * CH * NGRP, 256, 0, stream>>>(x, tw, X, featbf);
    k_mfma_mlp<FP, 0><<<63 * 4, 256, 0, stream>>>(featbf, wt1bf, b1, hbf, MROWS);
    k_mfma_mlp<HID, 1><<<63 * 4, 256, 0, stream>>>(hbf, wt2bf, b2, mobf, MROWS);
    k_cov<<<dim3(cnck, 4, BATCH), 512, 0, stream>>>(X, mobf, part, cck);
    k_cov_solve2<<<BATCH * 32, 512, 0, stream>>>(part, wc, cnck);
    k_istft_bf<<<BATCH * NGRP, 512, 0, stream>>>(X, wc, yfr);
    k_out<<<(BATCH * TLEN + 255) / 256, 256, 0, stream>>>(yfr, (float*)d_out);
}